// Round 1
// baseline (3094.061 us; speedup 1.0000x reference)
//
#include <hip/hip_runtime.h>
#include <math.h>

namespace {

constexpr int BB = 8;       // batch
constexpr int NN = 2048;    // input points
constexpr int NP = 1024;    // sampled points
constexpr int KS = 32;      // K neighbors
constexpr int CI = 128;     // C_IN
constexpr int CO = 256;     // C_OUT
constexpr int PL = 64;      // PLANES
constexpr int MD = 32;      // MID
constexpr int CN = 100;     // CURVE_NUM
constexpr int CLn = 5;      // CURVE_LEN
constexpr float R2v = 0.04f;
constexpr float EPSF = 1e-5f;

#define DEV static __device__ __forceinline__

DEV float lrelu(float x){ return x >= 0.0f ? x : 0.2f * x; }

DEV float wsum64(float v){
#pragma unroll
  for (int m = 32; m; m >>= 1) v += __shfl_xor(v, m, 64);
  return v;
}

DEV void argmax64(float& v, int& i){
#pragma unroll
  for (int m = 32; m; m >>= 1){
    float ov = __shfl_xor(v, m, 64);
    int   oi = __shfl_xor(i, m, 64);
    if (ov > v || (ov == v && oi < i)){ v = ov; i = oi; }
  }
}

// ---------------- FPS: 1 block per batch, sequential 1024 iterations -------
__global__ __launch_bounds__(1024) void k_fps(const float* __restrict__ xyz, int* __restrict__ fpsI){
  int b = blockIdx.x, t = threadIdx.x;
  const float* X = xyz + (size_t)b*3*NN;
  __shared__ float xs[NN], ys[NN], zs[NN];
  __shared__ float wv_[16]; __shared__ int wi_[16]; __shared__ int curs;
  for (int j = t; j < NN; j += 1024){ xs[j]=X[j]; ys[j]=X[NN+j]; zs[j]=X[2*NN+j]; }
  __syncthreads();
  float d0 = 1e10f, d1 = 1e10f;
  int p0 = t, p1 = t + 1024;
  int cur = 0, lane = t & 63, w = t >> 6;
  for (int it = 0; it < NP; ++it){
    if (t == 0) fpsI[b*NP + it] = cur;
    float cx = xs[cur], cy = ys[cur], cz = zs[cur];
    {
      float dx=__fsub_rn(xs[p0],cx), dy=__fsub_rn(ys[p0],cy), dz=__fsub_rn(zs[p0],cz);
      float dd=__fadd_rn(__fadd_rn(__fmul_rn(dx,dx),__fmul_rn(dy,dy)),__fmul_rn(dz,dz));
      d0 = fminf(d0, dd);
    }
    {
      float dx=__fsub_rn(xs[p1],cx), dy=__fsub_rn(ys[p1],cy), dz=__fsub_rn(zs[p1],cz);
      float dd=__fadd_rn(__fadd_rn(__fmul_rn(dx,dx),__fmul_rn(dy,dy)),__fmul_rn(dz,dz));
      d1 = fminf(d1, dd);
    }
    float v = d0; int vi = p0;
    if (d1 > v){ v = d1; vi = p1; }       // tie -> lower index p0
    argmax64(v, vi);
    if (lane == 0){ wv_[w] = v; wi_[w] = vi; }
    __syncthreads();
    if (t == 0){
      float bv = wv_[0]; int bi = wi_[0];
#pragma unroll
      for (int q=1;q<16;++q){ float qv=wv_[q]; int qi=wi_[q]; if (qv>bv || (qv==bv && qi<bi)){bv=qv;bi=qi;} }
      curs = bi;
    }
    __syncthreads();
    cur = curs;
  }
}

// ---------------- per-point squared norms of xyz ----------------------------
__global__ void k_sx(const float* __restrict__ xyz, float* __restrict__ sx){
  int u = blockIdx.x*256 + threadIdx.x; if (u >= BB*NN) return;
  int b = u / NN, n = u % NN;
  const float* X = xyz + (size_t)b*3*NN;
  float x=X[n], y=X[NN+n], z=X[2*NN+n];
  sx[u] = __fadd_rn(__fadd_rn(__fmul_rn(x,x),__fmul_rn(y,y)),__fmul_rn(z,z));
}

// ---------------- gather sampled coords + norms -----------------------------
__global__ void k_newxyz(const float* __restrict__ xyz, const int* __restrict__ fpsI,
                         float* __restrict__ nxyz, float* __restrict__ nxx){
  int u = blockIdx.x*256+threadIdx.x; if (u >= BB*NP) return;
  int b = u / NP;
  int i = fpsI[u];
  const float* X = xyz + (size_t)b*3*NN;
  float x=X[i], y=X[NN+i], z=X[2*NN+i];
  nxyz[u*3]=x; nxyz[u*3+1]=y; nxyz[u*3+2]=z;
  nxx[u] = __fadd_rn(__fadd_rn(__fmul_rn(x,x),__fmul_rn(y,y)),__fmul_rn(z,z));
}

// ---------------- ball query: first 32 in-radius indices in index order -----
__global__ __launch_bounds__(256) void k_ball(const float* __restrict__ xyz, const float* __restrict__ sx,
                      const float* __restrict__ nxyz, const float* __restrict__ nxx,
                      int* __restrict__ gidx){
  __shared__ int lists[4][KS];
  int t = threadIdx.x, w = t>>6, lane = t&63;
  int s = blockIdx.x*4 + w;
  int b = s >> 10;
  const float* X = xyz + (size_t)b*3*NN;
  float cx = nxyz[s*3], cy = nxyz[s*3+1], cz = nxyz[s*3+2];
  float cn = nxx[s];
  unsigned long long lmask = (lane == 63) ? 0x7fffffffffffffffull : ((1ull<<lane)-1ull);
  int cnt = 0;
  for (int ch = 0; ch < NN/64; ++ch){
    int n = ch*64 + lane;
    float px = X[n], py = X[NN+n], pz = X[2*NN+n];
    float dot = __fadd_rn(__fadd_rn(__fmul_rn(cx,px),__fmul_rn(cy,py)),__fmul_rn(cz,pz));
    float sqr = __fsub_rn(__fadd_rn(cn, sx[b*NN + n]), __fmul_rn(2.0f, dot));
    bool inr = !(sqr > R2v);
    unsigned long long m = __ballot(inr);
    if (inr){
      int slot = cnt + __popcll(m & lmask);
      if (slot < KS) lists[w][slot] = n;
    }
    cnt += __popcll(m);
    if (cnt >= KS) break;
  }
  int take = cnt < KS ? cnt : KS;
  if (lane < KS){
    gidx[(size_t)s*KS + lane] = lists[w][lane < take ? lane : 0];
  }
}

// ---------------- transpose x (B,128,2048) -> xt (B,2048,128) ---------------
__global__ __launch_bounds__(256) void k_transpose(const float* __restrict__ x, float* __restrict__ xt){
  __shared__ float tile[32][33];
  int blk = blockIdx.x;
  int b = blk >> 8;
  int r = blk & 255;
  int nt = r >> 2, ct = r & 3;
  int tx = threadIdx.x & 31, ty = threadIdx.x >> 5;
  const float* Xb = x + (size_t)b*CI*NN;
#pragma unroll
  for (int q=0;q<4;++q){
    int row = ty + q*8;
    tile[row][tx] = Xb[(size_t)(ct*32+row)*NN + nt*32 + tx];
  }
  __syncthreads();
  float* Tb = xt + (size_t)b*NN*CI;
#pragma unroll
  for (int q=0;q<4;++q){
    int row = ty + q*8;
    Tb[(size_t)(nt*32+row)*CI + ct*32 + tx] = tile[tx][row];
  }
}

// ---------------- grouped gather + max over 32 neighbors --------------------
__global__ __launch_bounds__(128) void k_groupmax(const float* __restrict__ xt, const int* __restrict__ gidx,
                          float* __restrict__ xnew){
  int s = blockIdx.x;
  int b = s >> 10;
  int c = threadIdx.x;
  const int* gi = gidx + (size_t)s*KS;
  float m = -INFINITY;
#pragma unroll 4
  for (int k=0;k<KS;++k){
    int idx = gi[k];
    m = fmaxf(m, xt[((size_t)b*NN + idx)*CI + c]);
  }
  xnew[(size_t)s*CI + c] = m;
}

// ---------------- conv1 (64x128) + BN partials ------------------------------
__global__ __launch_bounds__(256) void k_conv1(const float* __restrict__ xnew, const float* __restrict__ w,
                       float* __restrict__ hraw, float* __restrict__ part){
  __shared__ float wl[PL*129];
  __shared__ float xr[4][CI];
  __shared__ float ssm[4][PL], sq[4][PL];
  int t = threadIdx.x, wid = t>>6, lane = t&63;
  for (int u=t; u<PL*CI; u+=256){ int c=u>>7, i=u&127; wl[c*129+i] = w[u]; }
  int pt = blockIdx.x*4 + wid;
  xr[wid][lane]      = xnew[(size_t)pt*CI + lane];
  xr[wid][lane+64]   = xnew[(size_t)pt*CI + lane + 64];
  __syncthreads();
  float acc = 0.f;
  for (int i=0;i<CI;++i) acc = __fadd_rn(acc, __fmul_rn(wl[lane*129+i], xr[wid][i]));
  hraw[(size_t)pt*PL + lane] = acc;
  ssm[wid][lane] = acc; sq[wid][lane] = acc*acc;
  __syncthreads();
  if (t < PL){
    float s=0,q=0;
#pragma unroll
    for (int k=0;k<4;++k){ s+=ssm[k][t]; q+=sq[k][t]; }
    part[((size_t)blockIdx.x*PL + t)*2]   = s;
    part[((size_t)blockIdx.x*PL + t)*2+1] = q;
  }
}

// ---------------- generic partial reducer: one block per slot ---------------
__global__ __launch_bounds__(256) void k_red(const float* __restrict__ part, float* __restrict__ mv,
                     int nblk, int C2){
  int slot = blockIdx.x;
  __shared__ float red[256];
  float s = 0;
  for (int i = threadIdx.x; i < nblk; i += 256) s += part[(size_t)i*C2 + slot];
  red[threadIdx.x] = s; __syncthreads();
  for (int off=128; off; off>>=1){ if (threadIdx.x < off) red[threadIdx.x] += red[threadIdx.x+off]; __syncthreads(); }
  if (threadIdx.x==0) mv[slot] = red[0];
}

// ---------------- normalize conv1 + lrelu + x_att + walk feats --------------
__global__ __launch_bounds__(256) void k_n1(const float* __restrict__ hraw, const float* __restrict__ mv,
                    const float* __restrict__ g, const float* __restrict__ bb_, const float* __restrict__ attw,
                    float* __restrict__ h, float* __restrict__ attv, float* __restrict__ wxt){
  int t=threadIdx.x, wid=t>>6, lane=t&63;
  int pt = blockIdx.x*4 + wid;
  float x = hraw[(size_t)pt*PL + lane];
  float m = mv[2*lane] * (1.0f/8192.0f);
  float var = fmaxf(mv[2*lane+1]*(1.0f/8192.0f) - m*m, 0.f);
  float rs = 1.0f/sqrtf(var + EPSF);
  float hv = lrelu(__fadd_rn(__fmul_rn(__fmul_rn(__fsub_rn(x,m),rs), g[lane]), bb_[lane]));
  h[(size_t)pt*PL + lane] = hv;
  float dotv = wsum64(__fmul_rn(hv, attw[lane]));
  float att = 1.0f/(1.0f + expf(-dotv));
  if (lane==0) attv[pt] = att;
  wxt[(size_t)pt*PL + lane] = __fmul_rn(hv, att);
}

// ---------------- kNN top-33 per sampled point ------------------------------
__global__ __launch_bounds__(256) void k_knn(const float* __restrict__ nxyz, const float* __restrict__ nxx,
                     int* __restrict__ knnI){
  int t=threadIdx.x, wid=t>>6, lane=t&63;
  int gn = blockIdx.x*4 + wid;
  int b = gn >> 10;
  float cx = nxyz[(size_t)gn*3], cy=nxyz[(size_t)gn*3+1], cz=nxyz[(size_t)gn*3+2];
  float xn = nxx[gn];
  float vals[16];
#pragma unroll
  for (int q=0;q<16;++q){
    int mm = b*NP + q*64 + lane;
    float px=nxyz[(size_t)mm*3], py=nxyz[(size_t)mm*3+1], pz=nxyz[(size_t)mm*3+2];
    float dot = __fadd_rn(__fadd_rn(__fmul_rn(cx,px),__fmul_rn(cy,py)),__fmul_rn(cz,pz));
    vals[q] = __fsub_rn(__fsub_rn(__fmul_rn(2.0f,dot), xn), nxx[mm]);
  }
  int* out = knnI + (size_t)gn*33;
  for (int j=0;j<33;++j){
    float bv = -INFINITY; int bq = 0;
#pragma unroll
    for (int q=0;q<16;++q) if (vals[q] > bv){ bv = vals[q]; bq = q; }
    float v = bv; int vi = (bq<<6) | lane;
    argmax64(v, vi);
    if (lane == 0) out[j] = vi;
    if ((vi & 63) == lane){
      int wq = vi>>6;
#pragma unroll
      for (int q=0;q<16;++q) if (q==wq) vals[q] = -INFINITY;
    }
  }
}

// ---------------- top-100 start points per batch ----------------------------
__global__ __launch_bounds__(64) void k_start(const float* __restrict__ attv, int* __restrict__ startb){
  int b = blockIdx.x, lane = threadIdx.x;
  float vals[16];
#pragma unroll
  for (int q=0;q<16;++q) vals[q] = attv[b*NP + q*64 + lane];
  for (int j=0;j<CN;++j){
    float bv=-INFINITY; int bq=0;
#pragma unroll
    for (int q=0;q<16;++q) if (vals[q] > bv){ bv=vals[q]; bq=q; }
    float v=bv; int vi=(bq<<6)|lane;
    argmax64(v,vi);
    if (lane==0) startb[b*CN + j] = vi;
    if ((vi&63)==lane){
      int wq=vi>>6;
#pragma unroll
      for(int q=0;q<16;++q) if(q==wq) vals[q]=-INFINITY;
    }
  }
}

// ---------------- walk init ------------------------------------------------
__global__ __launch_bounds__(256) void k_w0(const float* __restrict__ wxt, const int* __restrict__ startb,
                    float* __restrict__ pre, int* __restrict__ curidx){
  int t=threadIdx.x, wid=t>>6, lane=t&63;
  int gc = blockIdx.x*4+wid;
  int b = gc/CN;
  int si = startb[gc];
  pre[(size_t)gc*PL + lane] = wxt[((size_t)b*NP+si)*PL + lane];
  if (lane==0) curidx[gc] = si;
}

// ---------------- walk momentum (single block) ------------------------------
__global__ __launch_bounds__(256) void k_wmom(const float* __restrict__ curf, float* __restrict__ pre,
                      const float* __restrict__ mw, const float* __restrict__ mg, const float* __restrict__ mb_){
  __shared__ float m0a[BB*CN], m1a[BB*CN];
  __shared__ float red[256][4];
  __shared__ float bc[4];
  int t = threadIdx.x;
  float s0=0,q0=0,s1=0,q1=0;
  for (int u=t; u<BB*CN; u+=256){
    const float* cf = curf + (size_t)u*PL;
    const float* pr = pre + (size_t)u*PL;
    float a0=0, a1=0;
    for (int i=0;i<PL;++i){ a0=__fadd_rn(a0,__fmul_rn(mw[i],cf[i]));     a1=__fadd_rn(a1,__fmul_rn(mw[128+i],cf[i])); }
    for (int i=0;i<PL;++i){ a0=__fadd_rn(a0,__fmul_rn(mw[64+i],pr[i]));  a1=__fadd_rn(a1,__fmul_rn(mw[192+i],pr[i])); }
    m0a[u]=a0; m1a[u]=a1;
    s0+=a0; q0+=a0*a0; s1+=a1; q1+=a1*a1;
  }
  red[t][0]=s0; red[t][1]=q0; red[t][2]=s1; red[t][3]=q1;
  __syncthreads();
  for (int off=128; off; off>>=1){
    if (t<off){ red[t][0]+=red[t+off][0]; red[t][1]+=red[t+off][1]; red[t][2]+=red[t+off][2]; red[t][3]+=red[t+off][3]; }
    __syncthreads();
  }
  if (t==0){
    float me0 = red[0][0]/800.0f, va0 = fmaxf(red[0][1]/800.0f - me0*me0, 0.f);
    float me1 = red[0][2]/800.0f, va1 = fmaxf(red[0][3]/800.0f - me1*me1, 0.f);
    bc[0]=me0; bc[1]=1.0f/sqrtf(va0+EPSF); bc[2]=me1; bc[3]=1.0f/sqrtf(va1+EPSF);
  }
  __syncthreads();
  float me0=bc[0], rs0=bc[1], me1=bc[2], rs1=bc[3];
  float g0=mg[0], g1=mg[1], b0=mb_[0], b1=mb_[1];
  for (int u=t; u<BB*CN; u+=256){
    float z0 = __fadd_rn(__fmul_rn(__fmul_rn(__fsub_rn(m0a[u],me0),rs0),g0), b0);
    float z1 = __fadd_rn(__fmul_rn(__fmul_rn(__fsub_rn(m1a[u],me1),rs1),g1), b1);
    float mx = fmaxf(z0,z1);
    float e0 = expf(z0-mx), e1 = expf(z1-mx);
    float se = e0+e1;
    float a0 = e0/se, a1 = e1/se;
    float* pr = pre + (size_t)u*PL;
    const float* cf = curf + (size_t)u*PL;
    for (int c=0;c<PL;++c) pr[c] = __fadd_rn(__fmul_rn(cf[c],a0), __fmul_rn(pr[c],a1));
  }
}

// ---------------- walk gather + agent logits + stats ------------------------
__global__ __launch_bounds__(256) void k_w2(const float* __restrict__ wxt, const float* __restrict__ pre,
                    const int* __restrict__ knnI, const int* __restrict__ curidx,
                    const float* __restrict__ aw,
                    float* __restrict__ pv, float* __restrict__ logitb, float* __restrict__ part){
  __shared__ float red[256];
  int t=threadIdx.x;
  int gc = blockIdx.x*8 + (t>>5);
  int k = t & 31;
  int b = gc/CN;
  int cc = curidx[gc];
  int nbr = knnI[((size_t)b*NP + cc)*33 + 1 + k];
  const float* row = wxt + ((size_t)b*NP + nbr)*PL;
  const float* pr = pre + (size_t)gc*PL;
  float* pvrow = pv + ((size_t)gc*KS + k)*PL;
  float acc=0;
  for (int i=0;i<PL;++i){ float v=row[i]; pvrow[i]=v; acc=__fadd_rn(acc,__fmul_rn(aw[i],v)); }
  for (int i=0;i<PL;++i){ acc=__fadd_rn(acc,__fmul_rn(aw[PL+i],pr[i])); }
  logitb[(size_t)gc*KS + k] = acc;
  red[t]=acc; __syncthreads();
  for (int off=128; off; off>>=1){ if(t<off) red[t]+=red[t+off]; __syncthreads(); }
  float tot = red[0];
  __syncthreads();
  red[t]=acc*acc; __syncthreads();
  for (int off=128; off; off>>=1){ if(t<off) red[t]+=red[t+off]; __syncthreads(); }
  if (t==0){ part[blockIdx.x*2]=tot; part[blockIdx.x*2+1]=red[0]; }
}

// ---------------- walk select (BN + d-factor + softmax + hard one-hot) ------
__global__ __launch_bounds__(64) void k_w3(const float* __restrict__ pv, const float* __restrict__ logitb,
                   const float* __restrict__ part, float* __restrict__ curf,
                   const float* __restrict__ pre, float* __restrict__ curves, int* __restrict__ curidx,
                   const float* __restrict__ ag, const float* __restrict__ ab_, int step){
  __shared__ int ks_;
  __shared__ float wv_;
  int gc = blockIdx.x;
  int lane = threadIdx.x;
  float s=0,q=0;
  for (int u=lane; u<100; u+=64){ s+=part[2*u]; q+=part[2*u+1]; }
  s = wsum64(s); q = wsum64(q);
  float me = s/25600.0f;
  float va = fmaxf(q/25600.0f - me*me, 0.f);
  float rs = 1.0f/sqrtf(va+EPSF);
  float g0 = ag[0], b0 = ab_[0];
  const float* pvB = pv + (size_t)gc*KS*PL;
  bool valid = lane < KS;
  float z = 0.f;
  if (valid){
    z = __fadd_rn(__fmul_rn(__fmul_rn(__fsub_rn(logitb[(size_t)gc*KS+lane], me), rs), g0), b0);
    if (step > 0){
      const float* cfo = curf + (size_t)gc*PL;
      const float* pr  = pre + (size_t)gc*PL;
      const float* pvr = pvB + (size_t)lane*PL;
      float dot=0, na=0, nn=0;
      for (int c=0;c<PL;++c){
        float acv = __fsub_rn(cfo[c], pr[c]);
        float nv  = __fsub_rn(pvr[c], cfo[c]);
        dot = __fadd_rn(dot, __fmul_rn(acv,nv));
        na  = __fadd_rn(na, __fmul_rn(acv,acv));
        nn  = __fadd_rn(nn, __fmul_rn(nv,nv));
      }
      float den = fmaxf(__fmul_rn(sqrtf(na), sqrtf(nn)), 1e-8f);
      float d = 1.0f + dot/den;
      d = fminf(fmaxf(d, 0.0f), 1.0f);
      z = __fmul_rn(z, d);
    }
  }
  float mz = valid ? z : -INFINITY;
#pragma unroll
  for (int m=16;m;m>>=1) mz = fmaxf(mz, __shfl_xor(mz, m, 32));
  float e = valid ? expf(z - mz) : 0.f;
  float se = e;
#pragma unroll
  for (int m=16;m;m>>=1) se += __shfl_xor(se, m, 32);
  float y = e / se;
  float bv = valid ? y : -INFINITY; int bi = valid ? lane : 999;
#pragma unroll
  for (int m=16;m;m>>=1){
    float ov=__shfl_xor(bv,m,32); int oi=__shfl_xor(bi,m,32);
    if (ov>bv || (ov==bv && oi<bi)){bv=ov;bi=oi;}
  }
  if (lane==0){
    ks_ = bi;
    wv_ = __fadd_rn(bv, __fsub_rn(1.0f, bv));
    curidx[gc] = bi;
  }
  __syncthreads();
  int kst = ks_; float wval = wv_;
  float val = __fmul_rn(pvB[(size_t)kst*PL + lane], wval);
  curf[(size_t)gc*PL + lane] = val;
  curves[((size_t)gc*CLn + step)*PL + lane] = val;
}

// ---------------- curve aggregation ----------------------------------------
__global__ void k_catt(const float* __restrict__ curves, const float* __restrict__ la, float* __restrict__ catt){
  int u = blockIdx.x*256+threadIdx.x; if (u >= BB*CN*CLn) return;
  const float* cr = curves + (size_t)u*PL;
  float a=0;
  for (int c=0;c<PL;++c) a = __fadd_rn(a, __fmul_rn(la[c], cr[c]));
  catt[u]=a;
}

__global__ __launch_bounds__(256) void k_inter(const float* __restrict__ curves, const float* __restrict__ catt,
                       float* __restrict__ inter0){
  int t=threadIdx.x, wid=t>>6, lane=t&63;
  int gc = blockIdx.x*4+wid;
  const float* at = catt + (size_t)gc*CLn;
  float a0=at[0],a1=at[1],a2=at[2],a3=at[3],a4=at[4];
  float mx = fmaxf(fmaxf(fmaxf(a0,a1),fmaxf(a2,a3)),a4);
  float e0=expf(a0-mx),e1=expf(a1-mx),e2=expf(a2-mx),e3=expf(a3-mx),e4=expf(a4-mx);
  float se = e0+e1+e2+e3+e4;
  const float* cr = curves + (size_t)gc*CLn*PL;
  float acc =           __fmul_rn(cr[lane],        e0/se);
  acc = __fadd_rn(acc, __fmul_rn(cr[PL+lane],     e1/se));
  acc = __fadd_rn(acc, __fmul_rn(cr[2*PL+lane],   e2/se));
  acc = __fadd_rn(acc, __fmul_rn(cr[3*PL+lane],   e3/se));
  acc = __fadd_rn(acc, __fmul_rn(cr[4*PL+lane],   e4/se));
  inter0[(size_t)gc*PL + lane] = acc;
}

__global__ __launch_bounds__(128) void k_intra(const float* __restrict__ curves, const float* __restrict__ catt,
                       float* __restrict__ intra0){
  __shared__ float va[CN], ya[CN];
  int blk = blockIdx.x;
  int b = blk/CLn, l = blk%CLn;
  int t = threadIdx.x;
  if (t < CN) va[t] = catt[(size_t)(b*CN+t)*CLn + l];
  __syncthreads();
  float mx = -INFINITY;
  for (int n=0;n<CN;++n) mx = fmaxf(mx, va[n]);
  if (t < CN) ya[t] = expf(va[t]-mx);
  __syncthreads();
  float se=0;
  for (int n=0;n<CN;++n) se += ya[n];
  if (t < PL){
    float acc=0;
    for (int n=0;n<CN;++n)
      acc = __fadd_rn(acc, __fmul_rn(curves[((size_t)(b*CN+n)*CLn + l)*PL + t], ya[n]/se));
    intra0[(size_t)blk*PL + t] = acc;
  }
}

__global__ __launch_bounds__(256) void k_inter1n(const float* __restrict__ inter0, const float* __restrict__ wa,
                         const float* __restrict__ wn, float* __restrict__ inter1, float* __restrict__ intern){
  __shared__ float i1[4][MD];
  int t=threadIdx.x, wid=t>>6, lane=t&63;
  int gc = blockIdx.x*4+wid;
  const float* r = inter0 + (size_t)gc*PL;
  if (lane < MD){
    float a=0;
    for (int c=0;c<PL;++c) a=__fadd_rn(a,__fmul_rn(wa[lane*PL+c], r[c]));
    inter1[(size_t)gc*MD+lane]=a;
    i1[wid][lane]=a;
  }
  __syncthreads();
  if (lane < MD){
    float a=0;
    for (int i=0;i<MD;++i) a=__fadd_rn(a,__fmul_rn(wn[lane*MD+i], i1[wid][i]));
    intern[(size_t)gc*MD+lane]=a;
  }
}

__global__ __launch_bounds__(64) void k_intra1l(const float* __restrict__ intra0, const float* __restrict__ wb,
                        const float* __restrict__ wl, float* __restrict__ intra1, float* __restrict__ intral){
  __shared__ float i1[MD];
  int blk=blockIdx.x, lane=threadIdx.x;
  const float* r = intra0 + (size_t)blk*PL;
  if (lane<MD){
    float a=0;
    for(int c=0;c<PL;++c) a=__fadd_rn(a,__fmul_rn(wb[lane*PL+c],r[c]));
    intra1[blk*MD+lane]=a; i1[lane]=a;
  }
  __syncthreads();
  if (lane<MD){
    float a=0;
    for(int i=0;i<MD;++i) a=__fadd_rn(a,__fmul_rn(wl[lane*MD+i],i1[i]));
    intral[blk*MD+lane]=a;
  }
}

__global__ __launch_bounds__(256) void k_ca5(const float* __restrict__ h, const float* __restrict__ inter1,
                     const float* __restrict__ intern, const float* __restrict__ intra1,
                     const float* __restrict__ intral, const float* __restrict__ wc,
                     const float* __restrict__ wd, float* __restrict__ yraw, float* __restrict__ part){
  __shared__ float i1[CN*33], in_[CN*33];
  __shared__ float t1[CLn*MD], tl[CLn*MD];
  __shared__ float wdl[PL*65];
  __shared__ float hrow[4][PL];
  __shared__ float xlb[4][MD];
  __shared__ float yb[4][CN];
  __shared__ float cfb[4][PL];
  __shared__ float ssm[4][PL], sq[4][PL];
  int t=threadIdx.x, wid=t>>6, lane=t&63;
  int pg = blockIdx.x;
  int b = pg >> 8;
  int p = (pg & 255)*4 + wid;
  for (int u=t; u<CN*MD; u+=256){ int n=u>>5, m=u&31; i1[n*33+m]=inter1[(size_t)b*CN*MD+u]; in_[n*33+m]=intern[(size_t)b*CN*MD+u]; }
  for (int u=t; u<CLn*MD; u+=256){ t1[u]=intra1[(size_t)b*CLn*MD+u]; tl[u]=intral[(size_t)b*CLn*MD+u]; }
  for (int u=t; u<PL*PL; u+=256){ int c=u>>6,i=u&63; wdl[c*65+i]=wd[u]; }
  hrow[wid][lane] = h[((size_t)b*NP+p)*PL + lane];
  __syncthreads();
  if (lane < MD){
    float a=0;
    for (int c=0;c<PL;++c) a = fmaf(wc[lane*PL+c], hrow[wid][c], a);
    xlb[wid][lane]=a;
  }
  __syncthreads();
  float s0, s1=-INFINITY;
  {
    float a=0;
    for (int m=0;m<MD;++m) a = fmaf(xlb[wid][m], i1[lane*33+m], a);
    s0=a;
    if (lane < CN-64){
      float a2=0; int n2=lane+64;
      for (int m=0;m<MD;++m) a2 = fmaf(xlb[wid][m], i1[n2*33+m], a2);
      s1=a2;
    }
  }
  float mx = fmaxf(s0, s1);
#pragma unroll
  for (int m=32;m;m>>=1) mx = fmaxf(mx, __shfl_xor(mx,m,64));
  float e0 = expf(s0-mx);
  float e1 = (lane < CN-64) ? expf(s1-mx) : 0.f;
  float se = e0+e1;
#pragma unroll
  for (int m=32;m;m>>=1) se += __shfl_xor(se,m,64);
  yb[wid][lane] = e0/se;
  if (lane < CN-64) yb[wid][64+lane] = e1/se;
  __syncthreads();
  if (lane < MD){
    float a=0;
    for (int n=0;n<CN;++n) a = fmaf(yb[wid][n], in_[n*33+lane], a);
    cfb[wid][lane] = a;
  }
  {
    float sl[CLn];
#pragma unroll
    for (int l=0;l<CLn;++l){
      float a=0;
      for (int m=0;m<MD;++m) a = fmaf(xlb[wid][m], t1[l*MD+m], a);
      sl[l]=a;
    }
    float mx2 = fmaxf(fmaxf(fmaxf(sl[0],sl[1]),fmaxf(sl[2],sl[3])),sl[4]);
    float es[CLn]; float ss2=0;
#pragma unroll
    for(int l=0;l<CLn;++l){ es[l]=expf(sl[l]-mx2); ss2+=es[l]; }
    if (lane < MD){
      float a=0;
#pragma unroll
      for (int l=0;l<CLn;++l) a = fmaf(es[l]/ss2, tl[l*MD+lane], a);
      cfb[wid][MD+lane] = a;
    }
  }
  __syncthreads();
  float acc=0;
  for (int i=0;i<PL;++i) acc = fmaf(wdl[lane*65+i], cfb[wid][i], acc);
  yraw[((size_t)b*NP+p)*PL + lane] = acc;
  ssm[wid][lane]=acc; sq[wid][lane]=acc*acc;
  __syncthreads();
  if (t < PL){
    float s2=0,q2=0;
#pragma unroll
    for (int k2=0;k2<4;++k2){ s2+=ssm[k2][t]; q2+=sq[k2][t]; }
    part[((size_t)pg*PL+t)*2]=s2; part[((size_t)pg*PL+t)*2+1]=q2;
  }
}

__global__ __launch_bounds__(256) void k_ca7(const float* __restrict__ h, const float* __restrict__ yraw,
                     const float* __restrict__ mv, const float* __restrict__ dg, const float* __restrict__ db,
                     float* __restrict__ h2){
  int u = blockIdx.x*256+threadIdx.x;
  int c = u & 63;
  float m = mv[2*c]*(1.0f/8192.0f);
  float va = fmaxf(mv[2*c+1]*(1.0f/8192.0f)-m*m, 0.f);
  float rs = 1.0f/sqrtf(va+EPSF);
  float y = yraw[u];
  float v = __fadd_rn(h[u], __fadd_rn(__fmul_rn(__fmul_rn(__fsub_rn(y,m),rs),dg[c]), db[c]));
  h2[u] = lrelu(v);
}

// ---------------- LPFA: staged recompute, wave per point --------------------
template<int STAGE>
__global__ __launch_bounds__(256) void k_lp(const float* __restrict__ nxyz, const int* __restrict__ knnI,
                    const float* __restrict__ h2,
                    const float* __restrict__ xw, const float* __restrict__ w1, const float* __restrict__ w2,
                    const float* __restrict__ mv1, const float* __restrict__ mv2, const float* __restrict__ mv3,
                    const float* __restrict__ g1, const float* __restrict__ b1,
                    const float* __restrict__ g2, const float* __restrict__ b2,
                    const float* __restrict__ g3, const float* __restrict__ b3,
                    float* __restrict__ part, float* __restrict__ lpout){
  __shared__ float pfb[4][KS*10];
  __shared__ int   nbl[4][KS];
  __shared__ __align__(16) float fbuf[4][PL*36];
  __shared__ float ssm[4][PL], sq[4][PL];
  int t=threadIdx.x, wid=t>>6, lane=t&63;
  int pt = blockIdx.x*4+wid;
  int b = pt >> 10;
  if (lane < KS){
    int nb = knnI[(size_t)pt*33 + lane];
    nbl[wid][lane] = nb;
    float cx=nxyz[(size_t)pt*3], cy=nxyz[(size_t)pt*3+1], cz=nxyz[(size_t)pt*3+2];
    size_t nbg = (size_t)b*NP + nb;
    float nx=nxyz[nbg*3], ny=nxyz[nbg*3+1], nz=nxyz[nbg*3+2];
    float* pf = &pfb[wid][lane*10];
    pf[0]=cx; pf[1]=cy; pf[2]=cz; pf[3]=nx; pf[4]=ny; pf[5]=nz;
    pf[6]=__fsub_rn(nx,cx); pf[7]=__fsub_rn(ny,cy); pf[8]=__fsub_rn(nz,cz);
  }
  __syncthreads();
  float xwr[9];
#pragma unroll
  for (int i=0;i<9;++i) xwr[i] = xw[lane*9+i];
  float c1v[KS];
#pragma unroll
  for (int j=0;j<KS;++j){
    float a=0;
#pragma unroll
    for (int i=0;i<9;++i) a = fmaf(xwr[i], pfb[wid][j*10+i], a);
    c1v[j]=a;
  }
  if (STAGE == 1){
    float s=0,qq=0;
#pragma unroll
    for (int j=0;j<KS;++j){ s+=c1v[j]; qq+=c1v[j]*c1v[j]; }
    ssm[wid][lane]=s; sq[wid][lane]=qq;
    __syncthreads();
    if (t<PL){
      float s2=0,q2=0;
#pragma unroll
      for(int k2=0;k2<4;++k2){s2+=ssm[k2][t];q2+=sq[k2][t];}
      part[((size_t)blockIdx.x*PL+t)*2]=s2; part[((size_t)blockIdx.x*PL+t)*2+1]=q2;
    }
    return;
  }
  constexpr float CT = 1.0f/262144.0f;
  float m1 = mv1[2*lane]*CT; float va1=fmaxf(mv1[2*lane+1]*CT-m1*m1,0.f); float rs1=1.0f/sqrtf(va1+EPSF);
  float hc = h2[(size_t)pt*PL + lane];
  float g1v=g1[lane], b1v=b1[lane];
#pragma unroll
  for (int j=0;j<KS;++j){
    float fd = __fsub_rn(h2[((size_t)b*NP + nbl[wid][j])*PL + lane], hc);
    float bn1 = __fadd_rn(__fmul_rn(__fmul_rn(__fsub_rn(c1v[j],m1),rs1),g1v),b1v);
    fbuf[wid][lane*36+j] = lrelu(__fadd_rn(fd, bn1));
  }
  __syncthreads();
  float wr[PL];
#pragma unroll
  for (int i=0;i<PL;++i) wr[i] = w1[lane*PL+i];
  float acc[KS];
#pragma unroll
  for (int j=0;j<KS;++j) acc[j]=0;
#pragma unroll
  for (int cp=0;cp<PL;++cp){
    const float4* rp = reinterpret_cast<const float4*>(&fbuf[wid][cp*36]);
    float wv = wr[cp];
#pragma unroll
    for (int j4=0;j4<8;++j4){
      float4 f = rp[j4];
      acc[j4*4+0] = fmaf(wv, f.x, acc[j4*4+0]);
      acc[j4*4+1] = fmaf(wv, f.y, acc[j4*4+1]);
      acc[j4*4+2] = fmaf(wv, f.z, acc[j4*4+2]);
      acc[j4*4+3] = fmaf(wv, f.w, acc[j4*4+3]);
    }
  }
  if (STAGE == 2){
    float s=0,qq=0;
#pragma unroll
    for (int j=0;j<KS;++j){ s+=acc[j]; qq+=acc[j]*acc[j]; }
    ssm[wid][lane]=s; sq[wid][lane]=qq;
    __syncthreads();
    if (t<PL){
      float s2=0,q2=0;
#pragma unroll
      for(int k2=0;k2<4;++k2){s2+=ssm[k2][t];q2+=sq[k2][t];}
      part[((size_t)blockIdx.x*PL+t)*2]=s2; part[((size_t)blockIdx.x*PL+t)*2+1]=q2;
    }
    return;
  }
  float m2 = mv2[2*lane]*CT; float va2=fmaxf(mv2[2*lane+1]*CT-m2*m2,0.f); float rs2=1.0f/sqrtf(va2+EPSF);
  float g2v=g2[lane], b2v=b2[lane];
  __syncthreads();
#pragma unroll
  for (int j=0;j<KS;++j){
    float f2 = lrelu(__fadd_rn(__fmul_rn(__fmul_rn(__fsub_rn(acc[j],m2),rs2),g2v),b2v));
    fbuf[wid][lane*36+j] = f2;
  }
  __syncthreads();
#pragma unroll
  for (int i=0;i<PL;++i) wr[i] = w2[lane*PL+i];
#pragma unroll
  for (int j=0;j<KS;++j) acc[j]=0;
#pragma unroll
  for (int cp=0;cp<PL;++cp){
    const float4* rp = reinterpret_cast<const float4*>(&fbuf[wid][cp*36]);
    float wv = wr[cp];
#pragma unroll
    for (int j4=0;j4<8;++j4){
      float4 f = rp[j4];
      acc[j4*4+0] = fmaf(wv, f.x, acc[j4*4+0]);
      acc[j4*4+1] = fmaf(wv, f.y, acc[j4*4+1]);
      acc[j4*4+2] = fmaf(wv, f.z, acc[j4*4+2]);
      acc[j4*4+3] = fmaf(wv, f.w, acc[j4*4+3]);
    }
  }
  if (STAGE == 3){
    float s=0,qq=0;
#pragma unroll
    for (int j=0;j<KS;++j){ s+=acc[j]; qq+=acc[j]*acc[j]; }
    ssm[wid][lane]=s; sq[wid][lane]=qq;
    __syncthreads();
    if (t<PL){
      float s2=0,q2=0;
#pragma unroll
      for(int k2=0;k2<4;++k2){s2+=ssm[k2][t];q2+=sq[k2][t];}
      part[((size_t)blockIdx.x*PL+t)*2]=s2; part[((size_t)blockIdx.x*PL+t)*2+1]=q2;
    }
    return;
  }
  float m3 = mv3[2*lane]*CT; float va3=fmaxf(mv3[2*lane+1]*CT-m3*m3,0.f); float rs3=1.0f/sqrtf(va3+EPSF);
  float g3v=g3[lane], b3v=b3[lane];
  float sum=0;
#pragma unroll
  for (int j=0;j<KS;++j){
    float f3 = lrelu(__fadd_rn(__fmul_rn(__fmul_rn(__fsub_rn(acc[j],m3),rs3),g3v),b3v));
    sum = __fadd_rn(sum, f3);
  }
  lpout[(size_t)pt*PL + lane] = __fmul_rn(sum, (1.0f/32.0f));
}

// ---------------- output convs ----------------------------------------------
__global__ __launch_bounds__(256) void k_fc1(const float* __restrict__ lpout, const float* __restrict__ w,
                     float* __restrict__ y2raw, float* __restrict__ part){
  __shared__ float wl[128*65];
  __shared__ float xr[4][PL];
  __shared__ float ssm[4][128], sq[4][128];
  int t=threadIdx.x, wid=t>>6, lane=t&63;
  int pg = blockIdx.x >> 1;
  int half = blockIdx.x & 1;
  int pt = pg*4 + wid;
  for (int u=t; u<128*PL; u+=256){ int c=u>>6, i=u&63; wl[c*65+i] = w[(size_t)half*128*PL + u]; }
  xr[wid][lane] = lpout[(size_t)pt*PL + lane];
  __syncthreads();
  float a0=0, a1=0;
  for (int i=0;i<PL;++i){
    float xv = xr[wid][i];
    a0 = fmaf(wl[lane*65+i], xv, a0);
    a1 = fmaf(wl[(lane+64)*65+i], xv, a1);
  }
  y2raw[(size_t)pt*CO + half*128 + lane]      = a0;
  y2raw[(size_t)pt*CO + half*128 + 64 + lane] = a1;
  ssm[wid][lane]=a0; ssm[wid][64+lane]=a1; sq[wid][lane]=a0*a0; sq[wid][64+lane]=a1*a1;
  __syncthreads();
  if (t < 128){
    float s=0,qq=0;
#pragma unroll
    for(int k2=0;k2<4;++k2){ s+=ssm[k2][t]; qq+=sq[k2][t]; }
    part[((size_t)pg*CO + half*128 + t)*2]   = s;
    part[((size_t)pg*CO + half*128 + t)*2+1] = qq;
  }
}

__global__ __launch_bounds__(256) void k_fc2(const float* __restrict__ xnew, const float* __restrict__ w,
                     float* __restrict__ scraw, float* __restrict__ part){
  __shared__ float wl[64*129];
  __shared__ float xr[4][CI];
  __shared__ float ssm[4][64], sq[4][64];
  int t=threadIdx.x, wid=t>>6, lane=t&63;
  int pg = blockIdx.x >> 2;
  int qr = blockIdx.x & 3;
  int pt = pg*4 + wid;
  for (int u=t; u<64*CI; u+=256){ int c=u>>7, i=u&127; wl[c*129+i] = w[(size_t)qr*64*CI + u]; }
  xr[wid][lane]    = xnew[(size_t)pt*CI+lane];
  xr[wid][lane+64] = xnew[(size_t)pt*CI+lane+64];
  __syncthreads();
  float a=0;
  for (int i=0;i<CI;++i) a = fmaf(wl[lane*129+i], xr[wid][i], a);
  scraw[(size_t)pt*CO + qr*64 + lane] = a;
  ssm[wid][lane]=a; sq[wid][lane]=a*a;
  __syncthreads();
  if (t<64){
    float s=0,qq=0;
#pragma unroll
    for(int k2=0;k2<4;++k2){ s+=ssm[k2][t]; qq+=sq[k2][t]; }
    part[((size_t)pg*CO + qr*64 + t)*2]   = s;
    part[((size_t)pg*CO + qr*64 + t)*2+1] = qq;
  }
}

__global__ __launch_bounds__(256) void k_fc3(const float* __restrict__ y2raw, const float* __restrict__ scraw,
                     const float* __restrict__ mvfc, const float* __restrict__ mvsc,
                     const float* __restrict__ g2, const float* __restrict__ b2,
                     const float* __restrict__ gs, const float* __restrict__ bs,
                     float* __restrict__ outp){
  int u = blockIdx.x*256+threadIdx.x;
  int p = u & 1023;
  int c = (u >> 10) & 255;
  int b = u >> 18;
  float mo = mvfc[2*c]*(1.0f/8192.0f); float vo=fmaxf(mvfc[2*c+1]*(1.0f/8192.0f)-mo*mo,0.f); float ro=1.0f/sqrtf(vo+EPSF);
  float ms = mvsc[2*c]*(1.0f/8192.0f); float vs=fmaxf(mvsc[2*c+1]*(1.0f/8192.0f)-ms*ms,0.f); float rs=1.0f/sqrtf(vs+EPSF);
  float y = y2raw[((size_t)b*NP+p)*CO + c];
  float s = scraw[((size_t)b*NP+p)*CO + c];
  float v1 = __fadd_rn(__fmul_rn(__fmul_rn(__fsub_rn(y,mo),ro),g2[c]), b2[c]);
  float v2 = __fadd_rn(__fmul_rn(__fmul_rn(__fsub_rn(s,ms),rs),gs[c]), bs[c]);
  outp[u] = lrelu(__fadd_rn(v1,v2));
}

__global__ void k_xyzd(const float* __restrict__ nxyz, float* __restrict__ outp){
  int u = blockIdx.x*256+threadIdx.x; if (u >= BB*3*NP) return;
  int s = u & 1023;
  int c = (u>>10)%3;
  int b = u/(3*NP);
  outp[u] = nxyz[((size_t)b*NP+s)*3 + c];
}

} // anonymous namespace

extern "C" void kernel_launch(void* const* d_in, const int* in_sizes, int n_in,
                              void* d_out, int out_size, void* d_ws, size_t ws_size,
                              hipStream_t stream){
  const float* xyz  = (const float*)d_in[0];
  const float* xin  = (const float*)d_in[1];
  const float* c1w  = (const float*)d_in[2];
  const float* c1g  = (const float*)d_in[3];
  const float* c1b  = (const float*)d_in[4];
  const float* c2w  = (const float*)d_in[5];
  const float* c2g  = (const float*)d_in[6];
  const float* c2b  = (const float*)d_in[7];
  const float* scw  = (const float*)d_in[8];
  const float* scg  = (const float*)d_in[9];
  const float* scb  = (const float*)d_in[10];
  const float* attw = (const float*)d_in[11];
  const float* aw   = (const float*)d_in[12];
  const float* ag   = (const float*)d_in[13];
  const float* abv  = (const float*)d_in[14];
  const float* mw   = (const float*)d_in[15];
  const float* mg   = (const float*)d_in[16];
  const float* mb_  = (const float*)d_in[17];
  const float* law  = (const float*)d_in[18];
  const float* waw  = (const float*)d_in[19];
  const float* wbw  = (const float*)d_in[20];
  const float* wcw  = (const float*)d_in[21];
  const float* wnw  = (const float*)d_in[22];
  const float* wlw  = (const float*)d_in[23];
  const float* wdw  = (const float*)d_in[24];
  const float* dg   = (const float*)d_in[25];
  const float* db   = (const float*)d_in[26];
  const float* xfw  = (const float*)d_in[27];
  const float* xfg  = (const float*)d_in[28];
  const float* xfb  = (const float*)d_in[29];
  const float* m1w  = (const float*)d_in[30];
  const float* m1g  = (const float*)d_in[31];
  const float* m1b  = (const float*)d_in[32];
  const float* m2w  = (const float*)d_in[33];
  const float* m2g  = (const float*)d_in[34];
  const float* m2b  = (const float*)d_in[35];
  float* outp = (float*)d_out;

  char* base = (char*)d_ws;
  size_t off = 0;
  auto alloc = [&](size_t nbytes)->void*{ void* p = base + off; off = (off + nbytes + 255) & ~(size_t)255; return p; };
  int*   fpsI   = (int*)  alloc(sizeof(int)*BB*NP);
  float* sx     = (float*)alloc(sizeof(float)*BB*NN);
  float* nxyz   = (float*)alloc(sizeof(float)*BB*NP*3);
  float* nxx    = (float*)alloc(sizeof(float)*BB*NP);
  int*   gidx   = (int*)  alloc(sizeof(int)*BB*NP*KS);
  float* xt     = (float*)alloc(sizeof(float)*(size_t)BB*NN*CI);
  float* xnew   = (float*)alloc(sizeof(float)*(size_t)BB*NP*CI);
  float* hraw   = (float*)alloc(sizeof(float)*(size_t)BB*NP*PL);
  float* hbuf   = (float*)alloc(sizeof(float)*(size_t)BB*NP*PL);
  float* attv   = (float*)alloc(sizeof(float)*BB*NP);
  float* wxt    = (float*)alloc(sizeof(float)*(size_t)BB*NP*PL);
  int*   knnI   = (int*)  alloc(sizeof(int)*BB*NP*33);
  int*   startb = (int*)  alloc(sizeof(int)*BB*CN);
  float* pre    = (float*)alloc(sizeof(float)*BB*CN*PL);
  float* curf   = (float*)alloc(sizeof(float)*BB*CN*PL);
  int*   curidx = (int*)  alloc(sizeof(int)*BB*CN);
  float* pv     = (float*)alloc(sizeof(float)*(size_t)BB*CN*KS*PL);
  float* logitb = (float*)alloc(sizeof(float)*BB*CN*KS);
  float* curves = (float*)alloc(sizeof(float)*BB*CN*CLn*PL);
  float* catt   = (float*)alloc(sizeof(float)*BB*CN*CLn);
  float* inter0 = (float*)alloc(sizeof(float)*BB*CN*PL);
  float* intra0 = (float*)alloc(sizeof(float)*BB*CLn*PL);
  float* inter1 = (float*)alloc(sizeof(float)*BB*CN*MD);
  float* intern = (float*)alloc(sizeof(float)*BB*CN*MD);
  float* intra1 = (float*)alloc(sizeof(float)*BB*CLn*MD);
  float* intral = (float*)alloc(sizeof(float)*BB*CLn*MD);
  float* yraw   = (float*)alloc(sizeof(float)*(size_t)BB*NP*PL);
  float* h2     = (float*)alloc(sizeof(float)*(size_t)BB*NP*PL);
  float* lpout  = (float*)alloc(sizeof(float)*(size_t)BB*NP*PL);
  float* y2raw  = (float*)alloc(sizeof(float)*(size_t)BB*NP*CO);
  float* scraw  = (float*)alloc(sizeof(float)*(size_t)BB*NP*CO);
  float* part   = (float*)alloc(sizeof(float)*(size_t)2048*CO*2);
  float* mvA    = (float*)alloc(sizeof(float)*2048);
  float* mvC1 = mvA;
  float* mvWD = mvA + 128;
  float* mvL1 = mvA + 256;
  float* mvL2 = mvA + 384;
  float* mvL3 = mvA + 512;
  float* mvFC = mvA + 640;
  float* mvSC = mvA + 1152;

  k_fps<<<BB, 1024, 0, stream>>>(xyz, fpsI);
  k_sx<<<(BB*NN)/256, 256, 0, stream>>>(xyz, sx);
  k_newxyz<<<(BB*NP)/256, 256, 0, stream>>>(xyz, fpsI, nxyz, nxx);
  k_ball<<<(BB*NP)/4, 256, 0, stream>>>(xyz, sx, nxyz, nxx, gidx);
  k_transpose<<<BB*256, 256, 0, stream>>>(xin, xt);
  k_groupmax<<<BB*NP, 128, 0, stream>>>(xt, gidx, xnew);
  k_conv1<<<(BB*NP)/4, 256, 0, stream>>>(xnew, c1w, hraw, part);
  k_red<<<128, 256, 0, stream>>>(part, mvC1, 2048, 128);
  k_n1<<<(BB*NP)/4, 256, 0, stream>>>(hraw, mvC1, c1g, c1b, attw, hbuf, attv, wxt);
  k_knn<<<(BB*NP)/4, 256, 0, stream>>>(nxyz, nxx, knnI);
  k_start<<<BB, 64, 0, stream>>>(attv, startb);
  k_w0<<<(BB*CN)/4, 256, 0, stream>>>(wxt, startb, pre, curidx);
  for (int step = 0; step < CLn; ++step){
    if (step > 0) k_wmom<<<1, 256, 0, stream>>>(curf, pre, mw, mg, mb_);
    k_w2<<<(BB*CN)/8, 256, 0, stream>>>(wxt, pre, knnI, curidx, aw, pv, logitb, part);
    k_w3<<<BB*CN, 64, 0, stream>>>(pv, logitb, part, curf, pre, curves, curidx, ag, abv, step);
  }
  k_catt<<<(BB*CN*CLn + 255)/256, 256, 0, stream>>>(curves, law, catt);
  k_inter<<<(BB*CN)/4, 256, 0, stream>>>(curves, catt, inter0);
  k_intra<<<BB*CLn, 128, 0, stream>>>(curves, catt, intra0);
  k_inter1n<<<(BB*CN)/4, 256, 0, stream>>>(inter0, waw, wnw, inter1, intern);
  k_intra1l<<<BB*CLn, 64, 0, stream>>>(intra0, wbw, wlw, intra1, intral);
  k_ca5<<<(BB*NP)/4, 256, 0, stream>>>(hbuf, inter1, intern, intra1, intral, wcw, wdw, yraw, part);
  k_red<<<128, 256, 0, stream>>>(part, mvWD, 2048, 128);
  k_ca7<<<(BB*NP*PL)/256, 256, 0, stream>>>(hbuf, yraw, mvWD, dg, db, h2);
  k_lp<1><<<(BB*NP)/4, 256, 0, stream>>>(nxyz, knnI, h2, xfw, m1w, m2w, mvL1, mvL2, mvL3, xfg, xfb, m1g, m1b, m2g, m2b, part, lpout);
  k_red<<<128, 256, 0, stream>>>(part, mvL1, 2048, 128);
  k_lp<2><<<(BB*NP)/4, 256, 0, stream>>>(nxyz, knnI, h2, xfw, m1w, m2w, mvL1, mvL2, mvL3, xfg, xfb, m1g, m1b, m2g, m2b, part, lpout);
  k_red<<<128, 256, 0, stream>>>(part, mvL2, 2048, 128);
  k_lp<3><<<(BB*NP)/4, 256, 0, stream>>>(nxyz, knnI, h2, xfw, m1w, m2w, mvL1, mvL2, mvL3, xfg, xfb, m1g, m1b, m2g, m2b, part, lpout);
  k_red<<<128, 256, 0, stream>>>(part, mvL3, 2048, 128);
  k_lp<4><<<(BB*NP)/4, 256, 0, stream>>>(nxyz, knnI, h2, xfw, m1w, m2w, mvL1, mvL2, mvL3, xfg, xfb, m1g, m1b, m2g, m2b, part, lpout);
  k_fc1<<<((BB*NP)/4)*2, 256, 0, stream>>>(lpout, c2w, y2raw, part);
  k_red<<<512, 256, 0, stream>>>(part, mvFC, 2048, 512);
  k_fc2<<<((BB*NP)/4)*4, 256, 0, stream>>>(xnew, scw, scraw, part);
  k_red<<<512, 256, 0, stream>>>(part, mvSC, 2048, 512);
  k_fc3<<<(BB*CO*NP)/256, 256, 0, stream>>>(y2raw, scraw, mvFC, mvSC, c2g, c2b, scg, scb, outp + BB*3*NP);
  k_xyzd<<<(BB*3*NP + 255)/256, 256, 0, stream>>>(nxyz, outp);
}

// Round 2
// 1573.299 us; speedup vs baseline: 1.9666x; 1.9666x over previous
//
#include <hip/hip_runtime.h>
#include <math.h>

namespace {

constexpr int BB = 8;       // batch
constexpr int NN = 2048;    // input points
constexpr int NP = 1024;    // sampled points
constexpr int KS = 32;      // K neighbors
constexpr int CI = 128;     // C_IN
constexpr int CO = 256;     // C_OUT
constexpr int PL = 64;      // PLANES
constexpr int MD = 32;      // MID
constexpr int CN = 100;     // CURVE_NUM
constexpr int CLn = 5;      // CURVE_LEN
constexpr float R2v = 0.04f;
constexpr float EPSF = 1e-5f;

#define DEV static __device__ __forceinline__

DEV float lrelu(float x){ return x >= 0.0f ? x : 0.2f * x; }

DEV float wsum64(float v){
#pragma unroll
  for (int m = 32; m; m >>= 1) v += __shfl_xor(v, m, 64);
  return v;
}

// ---- DPP wave-64 max-reduce of a packed u64 key (VALU-latency cross-lane) --
// gfx9 idiom: row_shr 1/2/4/8 then row_bcast15/31; result valid in lane 63,
// broadcast back via readlane. Max + tie-break is associative => bit-exact
// equivalent to the shfl_xor butterfly it replaces.
DEV unsigned long long dpp_wavemax_u64(unsigned long long v){
  unsigned hi = (unsigned)(v >> 32), lo = (unsigned)v;
#define DSTEP(ctrl) { \
    unsigned nhi = (unsigned)__builtin_amdgcn_update_dpp((int)hi, (int)hi, ctrl, 0xf, 0xf, false); \
    unsigned nlo = (unsigned)__builtin_amdgcn_update_dpp((int)lo, (int)lo, ctrl, 0xf, 0xf, false); \
    bool gt = (nhi > hi) || (nhi == hi && nlo > lo); \
    hi = gt ? nhi : hi; lo = gt ? nlo : lo; }
  DSTEP(0x111)  // row_shr:1
  DSTEP(0x112)  // row_shr:2
  DSTEP(0x114)  // row_shr:4
  DSTEP(0x118)  // row_shr:8
  DSTEP(0x142)  // row_bcast:15
  DSTEP(0x143)  // row_bcast:31
#undef DSTEP
  hi = (unsigned)__builtin_amdgcn_readlane((int)hi, 63);
  lo = (unsigned)__builtin_amdgcn_readlane((int)lo, 63);
  return ((unsigned long long)hi << 32) | lo;
}

// argmax across 64 lanes of (float value, int index), tie -> lowest index.
// Works for any finite/-inf floats via order-preserving key transform.
DEV int dpp_argmax_idx(float v, int idx){
  unsigned kb = __float_as_uint(v);
  kb = (kb & 0x80000000u) ? ~kb : (kb | 0x80000000u);
  unsigned long long p = ((unsigned long long)kb << 32) | (unsigned)~idx;
  return (int)~(unsigned)dpp_wavemax_u64(p);
}

// ---------------- FPS: 1 block (4 waves) per batch, 8 points/lane ----------
__global__ __launch_bounds__(256) void k_fps(const float* __restrict__ xyz, int* __restrict__ fpsI){
  int b = blockIdx.x, t = threadIdx.x, lane = t & 63, w = t >> 6;
  const float* X = xyz + (size_t)b*3*NN;
  __shared__ float4 cpk[NN];
  __shared__ unsigned long long slots[2][4];
  float px[8], py[8], pz[8], dd[8];
  int base = t*8;
#pragma unroll
  for (int j=0;j<8;++j){
    px[j] = X[base+j]; py[j] = X[NN+base+j]; pz[j] = X[2*NN+base+j];
    dd[j] = 1e10f;
    cpk[base+j] = make_float4(px[j], py[j], pz[j], 0.f);
  }
  __syncthreads();
  int cur = 0;
  for (int it = 0; it < NP; ++it){
    if (t == 0) fpsI[b*NP + it] = cur;
    float4 c = cpk[cur];                      // LDS broadcast (ds_read_b128)
    unsigned long long p[8];
#pragma unroll
    for (int j=0;j<8;++j){
      float dx=__fsub_rn(px[j],c.x), dy=__fsub_rn(py[j],c.y), dz=__fsub_rn(pz[j],c.z);
      float dn=__fadd_rn(__fadd_rn(__fmul_rn(dx,dx),__fmul_rn(dy,dy)),__fmul_rn(dz,dz));
      dd[j] = fminf(dd[j], dn);
      p[j] = ((unsigned long long)__float_as_uint(dd[j]) << 32) | (unsigned)~(base+j);
    }
#pragma unroll
    for (int j=0;j<4;++j) p[j] = p[j] > p[j+4] ? p[j] : p[j+4];
#pragma unroll
    for (int j=0;j<2;++j) p[j] = p[j] > p[j+2] ? p[j] : p[j+2];
    p[0] = p[0] > p[1] ? p[0] : p[1];
    unsigned long long wm = dpp_wavemax_u64(p[0]);
    if (lane == 0) slots[it & 1][w] = wm;
    __syncthreads();
    unsigned long long g = slots[it & 1][0];
    unsigned long long s1 = slots[it & 1][1]; if (s1 > g) g = s1;
    unsigned long long s2 = slots[it & 1][2]; if (s2 > g) g = s2;
    unsigned long long s3 = slots[it & 1][3]; if (s3 > g) g = s3;
    cur = (int)~(unsigned)g;
  }
}

// ---------------- per-point squared norms of xyz ----------------------------
__global__ void k_sx(const float* __restrict__ xyz, float* __restrict__ sx){
  int u = blockIdx.x*256 + threadIdx.x; if (u >= BB*NN) return;
  int b = u / NN, n = u % NN;
  const float* X = xyz + (size_t)b*3*NN;
  float x=X[n], y=X[NN+n], z=X[2*NN+n];
  sx[u] = __fadd_rn(__fadd_rn(__fmul_rn(x,x),__fmul_rn(y,y)),__fmul_rn(z,z));
}

// ---------------- gather sampled coords + norms -----------------------------
__global__ void k_newxyz(const float* __restrict__ xyz, const int* __restrict__ fpsI,
                         float* __restrict__ nxyz, float* __restrict__ nxx){
  int u = blockIdx.x*256+threadIdx.x; if (u >= BB*NP) return;
  int b = u / NP;
  int i = fpsI[u];
  const float* X = xyz + (size_t)b*3*NN;
  float x=X[i], y=X[NN+i], z=X[2*NN+i];
  nxyz[u*3]=x; nxyz[u*3+1]=y; nxyz[u*3+2]=z;
  nxx[u] = __fadd_rn(__fadd_rn(__fmul_rn(x,x),__fmul_rn(y,y)),__fmul_rn(z,z));
}

// ---------------- ball query: first 32 in-radius indices in index order -----
__global__ __launch_bounds__(256) void k_ball(const float* __restrict__ xyz, const float* __restrict__ sx,
                      const float* __restrict__ nxyz, const float* __restrict__ nxx,
                      int* __restrict__ gidx){
  __shared__ int lists[4][KS];
  int t = threadIdx.x, w = t>>6, lane = t&63;
  int s = blockIdx.x*4 + w;
  int b = s >> 10;
  const float* X = xyz + (size_t)b*3*NN;
  float cx = nxyz[s*3], cy = nxyz[s*3+1], cz = nxyz[s*3+2];
  float cn = nxx[s];
  unsigned long long lmask = (lane == 63) ? 0x7fffffffffffffffull : ((1ull<<lane)-1ull);
  int cnt = 0;
  for (int ch = 0; ch < NN/64; ++ch){
    int n = ch*64 + lane;
    float px = X[n], py = X[NN+n], pz = X[2*NN+n];
    float dot = __fadd_rn(__fadd_rn(__fmul_rn(cx,px),__fmul_rn(cy,py)),__fmul_rn(cz,pz));
    float sqr = __fsub_rn(__fadd_rn(cn, sx[b*NN + n]), __fmul_rn(2.0f, dot));
    bool inr = !(sqr > R2v);
    unsigned long long m = __ballot(inr);
    if (inr){
      int slot = cnt + __popcll(m & lmask);
      if (slot < KS) lists[w][slot] = n;
    }
    cnt += __popcll(m);
    if (cnt >= KS) break;
  }
  int take = cnt < KS ? cnt : KS;
  if (lane < KS){
    gidx[(size_t)s*KS + lane] = lists[w][lane < take ? lane : 0];
  }
}

// ---------------- transpose x (B,128,2048) -> xt (B,2048,128) ---------------
__global__ __launch_bounds__(256) void k_transpose(const float* __restrict__ x, float* __restrict__ xt){
  __shared__ float tile[32][33];
  int blk = blockIdx.x;
  int b = blk >> 8;
  int r = blk & 255;
  int nt = r >> 2, ct = r & 3;
  int tx = threadIdx.x & 31, ty = threadIdx.x >> 5;
  const float* Xb = x + (size_t)b*CI*NN;
#pragma unroll
  for (int q=0;q<4;++q){
    int row = ty + q*8;
    tile[row][tx] = Xb[(size_t)(ct*32+row)*NN + nt*32 + tx];
  }
  __syncthreads();
  float* Tb = xt + (size_t)b*NN*CI;
#pragma unroll
  for (int q=0;q<4;++q){
    int row = ty + q*8;
    Tb[(size_t)(nt*32+row)*CI + ct*32 + tx] = tile[tx][row];
  }
}

// ---------------- grouped gather + max over 32 neighbors --------------------
__global__ __launch_bounds__(128) void k_groupmax(const float* __restrict__ xt, const int* __restrict__ gidx,
                          float* __restrict__ xnew){
  int s = blockIdx.x;
  int b = s >> 10;
  int c = threadIdx.x;
  const int* gi = gidx + (size_t)s*KS;
  float m = -INFINITY;
#pragma unroll 4
  for (int k=0;k<KS;++k){
    int idx = gi[k];
    m = fmaxf(m, xt[((size_t)b*NN + idx)*CI + c]);
  }
  xnew[(size_t)s*CI + c] = m;
}

// ---------------- conv1 (64x128) + BN partials ------------------------------
__global__ __launch_bounds__(256) void k_conv1(const float* __restrict__ xnew, const float* __restrict__ w,
                       float* __restrict__ hraw, float* __restrict__ part){
  __shared__ float wl[PL*129];
  __shared__ float xr[4][CI];
  __shared__ float ssm[4][PL], sq[4][PL];
  int t = threadIdx.x, wid = t>>6, lane = t&63;
  for (int u=t; u<PL*CI; u+=256){ int c=u>>7, i=u&127; wl[c*129+i] = w[u]; }
  int pt = blockIdx.x*4 + wid;
  xr[wid][lane]      = xnew[(size_t)pt*CI + lane];
  xr[wid][lane+64]   = xnew[(size_t)pt*CI + lane + 64];
  __syncthreads();
  float acc = 0.f;
  for (int i=0;i<CI;++i) acc = __fadd_rn(acc, __fmul_rn(wl[lane*129+i], xr[wid][i]));
  hraw[(size_t)pt*PL + lane] = acc;
  ssm[wid][lane] = acc; sq[wid][lane] = acc*acc;
  __syncthreads();
  if (t < PL){
    float s=0,q=0;
#pragma unroll
    for (int k=0;k<4;++k){ s+=ssm[k][t]; q+=sq[k][t]; }
    part[((size_t)blockIdx.x*PL + t)*2]   = s;
    part[((size_t)blockIdx.x*PL + t)*2+1] = q;
  }
}

// ---------------- generic partial reducer: one block per slot ---------------
__global__ __launch_bounds__(256) void k_red(const float* __restrict__ part, float* __restrict__ mv,
                     int nblk, int C2){
  int slot = blockIdx.x;
  __shared__ float red[256];
  float s = 0;
  for (int i = threadIdx.x; i < nblk; i += 256) s += part[(size_t)i*C2 + slot];
  red[threadIdx.x] = s; __syncthreads();
  for (int off=128; off; off>>=1){ if (threadIdx.x < off) red[threadIdx.x] += red[threadIdx.x+off]; __syncthreads(); }
  if (threadIdx.x==0) mv[slot] = red[0];
}

// ---------------- normalize conv1 + lrelu + x_att + walk feats --------------
__global__ __launch_bounds__(256) void k_n1(const float* __restrict__ hraw, const float* __restrict__ mv,
                    const float* __restrict__ g, const float* __restrict__ bb_, const float* __restrict__ attw,
                    float* __restrict__ h, float* __restrict__ attv, float* __restrict__ wxt){
  int t=threadIdx.x, wid=t>>6, lane=t&63;
  int pt = blockIdx.x*4 + wid;
  float x = hraw[(size_t)pt*PL + lane];
  float m = mv[2*lane] * (1.0f/8192.0f);
  float var = fmaxf(mv[2*lane+1]*(1.0f/8192.0f) - m*m, 0.f);
  float rs = 1.0f/sqrtf(var + EPSF);
  float hv = lrelu(__fadd_rn(__fmul_rn(__fmul_rn(__fsub_rn(x,m),rs), g[lane]), bb_[lane]));
  h[(size_t)pt*PL + lane] = hv;
  float dotv = wsum64(__fmul_rn(hv, attw[lane]));
  float att = 1.0f/(1.0f + expf(-dotv));
  if (lane==0) attv[pt] = att;
  wxt[(size_t)pt*PL + lane] = __fmul_rn(hv, att);
}

// ---------------- kNN top-33 per sampled point ------------------------------
__global__ __launch_bounds__(256) void k_knn(const float* __restrict__ nxyz, const float* __restrict__ nxx,
                     int* __restrict__ knnI){
  int t=threadIdx.x, wid=t>>6, lane=t&63;
  int gn = blockIdx.x*4 + wid;
  int b = gn >> 10;
  float cx = nxyz[(size_t)gn*3], cy=nxyz[(size_t)gn*3+1], cz=nxyz[(size_t)gn*3+2];
  float xn = nxx[gn];
  float vals[16];
#pragma unroll
  for (int q=0;q<16;++q){
    int mm = b*NP + q*64 + lane;
    float px=nxyz[(size_t)mm*3], py=nxyz[(size_t)mm*3+1], pz=nxyz[(size_t)mm*3+2];
    float dot = __fadd_rn(__fadd_rn(__fmul_rn(cx,px),__fmul_rn(cy,py)),__fmul_rn(cz,pz));
    vals[q] = __fsub_rn(__fsub_rn(__fmul_rn(2.0f,dot), xn), nxx[mm]);
  }
  int* out = knnI + (size_t)gn*33;
  for (int j=0;j<33;++j){
    float bv = -INFINITY; int bq = 0;
#pragma unroll
    for (int q=0;q<16;++q) if (vals[q] > bv){ bv = vals[q]; bq = q; }
    int vi = dpp_argmax_idx(bv, (bq<<6) | lane);
    if (lane == 0) out[j] = vi;
    if ((vi & 63) == lane){
      int wq = vi>>6;
#pragma unroll
      for (int q=0;q<16;++q) if (q==wq) vals[q] = -INFINITY;
    }
  }
}

// ---------------- top-100 start points per batch ----------------------------
__global__ __launch_bounds__(64) void k_start(const float* __restrict__ attv, int* __restrict__ startb){
  int b = blockIdx.x, lane = threadIdx.x;
  float vals[16];
#pragma unroll
  for (int q=0;q<16;++q) vals[q] = attv[b*NP + q*64 + lane];
  for (int j=0;j<CN;++j){
    float bv=-INFINITY; int bq=0;
#pragma unroll
    for (int q=0;q<16;++q) if (vals[q] > bv){ bv=vals[q]; bq=q; }
    int vi = dpp_argmax_idx(bv, (bq<<6) | lane);
    if (lane==0) startb[b*CN + j] = vi;
    if ((vi&63)==lane){
      int wq=vi>>6;
#pragma unroll
      for(int q=0;q<16;++q) if(q==wq) vals[q]=-INFINITY;
    }
  }
}

// ---------------- walk init ------------------------------------------------
__global__ __launch_bounds__(256) void k_w0(const float* __restrict__ wxt, const int* __restrict__ startb,
                    float* __restrict__ pre, int* __restrict__ curidx){
  int t=threadIdx.x, wid=t>>6, lane=t&63;
  int gc = blockIdx.x*4+wid;
  int b = gc/CN;
  int si = startb[gc];
  pre[(size_t)gc*PL + lane] = wxt[((size_t)b*NP+si)*PL + lane];
  if (lane==0) curidx[gc] = si;
}

// ---------------- walk momentum (single block) ------------------------------
__global__ __launch_bounds__(256) void k_wmom(const float* __restrict__ curf, float* __restrict__ pre,
                      const float* __restrict__ mw, const float* __restrict__ mg, const float* __restrict__ mb_){
  __shared__ float m0a[BB*CN], m1a[BB*CN];
  __shared__ float red[256][4];
  __shared__ float bc[4];
  int t = threadIdx.x;
  float s0=0,q0=0,s1=0,q1=0;
  for (int u=t; u<BB*CN; u+=256){
    const float* cf = curf + (size_t)u*PL;
    const float* pr = pre + (size_t)u*PL;
    float a0=0, a1=0;
    for (int i=0;i<PL;++i){ a0=__fadd_rn(a0,__fmul_rn(mw[i],cf[i]));     a1=__fadd_rn(a1,__fmul_rn(mw[128+i],cf[i])); }
    for (int i=0;i<PL;++i){ a0=__fadd_rn(a0,__fmul_rn(mw[64+i],pr[i]));  a1=__fadd_rn(a1,__fmul_rn(mw[192+i],pr[i])); }
    m0a[u]=a0; m1a[u]=a1;
    s0+=a0; q0+=a0*a0; s1+=a1; q1+=a1*a1;
  }
  red[t][0]=s0; red[t][1]=q0; red[t][2]=s1; red[t][3]=q1;
  __syncthreads();
  for (int off=128; off; off>>=1){
    if (t<off){ red[t][0]+=red[t+off][0]; red[t][1]+=red[t+off][1]; red[t][2]+=red[t+off][2]; red[t][3]+=red[t+off][3]; }
    __syncthreads();
  }
  if (t==0){
    float me0 = red[0][0]/800.0f, va0 = fmaxf(red[0][1]/800.0f - me0*me0, 0.f);
    float me1 = red[0][2]/800.0f, va1 = fmaxf(red[0][3]/800.0f - me1*me1, 0.f);
    bc[0]=me0; bc[1]=1.0f/sqrtf(va0+EPSF); bc[2]=me1; bc[3]=1.0f/sqrtf(va1+EPSF);
  }
  __syncthreads();
  float me0=bc[0], rs0=bc[1], me1=bc[2], rs1=bc[3];
  float g0=mg[0], g1=mg[1], b0=mb_[0], b1=mb_[1];
  for (int u=t; u<BB*CN; u+=256){
    float z0 = __fadd_rn(__fmul_rn(__fmul_rn(__fsub_rn(m0a[u],me0),rs0),g0), b0);
    float z1 = __fadd_rn(__fmul_rn(__fmul_rn(__fsub_rn(m1a[u],me1),rs1),g1), b1);
    float mx = fmaxf(z0,z1);
    float e0 = expf(z0-mx), e1 = expf(z1-mx);
    float se = e0+e1;
    float a0 = e0/se, a1 = e1/se;
    float* pr = pre + (size_t)u*PL;
    const float* cf = curf + (size_t)u*PL;
    for (int c=0;c<PL;++c) pr[c] = __fadd_rn(__fmul_rn(cf[c],a0), __fmul_rn(pr[c],a1));
  }
}

// ---------------- walk gather + agent logits + stats ------------------------
__global__ __launch_bounds__(256) void k_w2(const float* __restrict__ wxt, const float* __restrict__ pre,
                    const int* __restrict__ knnI, const int* __restrict__ curidx,
                    const float* __restrict__ aw,
                    float* __restrict__ pv, float* __restrict__ logitb, float* __restrict__ part){
  __shared__ float red[256];
  int t=threadIdx.x;
  int gc = blockIdx.x*8 + (t>>5);
  int k = t & 31;
  int b = gc/CN;
  int cc = curidx[gc];
  int nbr = knnI[((size_t)b*NP + cc)*33 + 1 + k];
  const float* row = wxt + ((size_t)b*NP + nbr)*PL;
  const float* pr = pre + (size_t)gc*PL;
  float* pvrow = pv + ((size_t)gc*KS + k)*PL;
  float acc=0;
  for (int i=0;i<PL;++i){ float v=row[i]; pvrow[i]=v; acc=__fadd_rn(acc,__fmul_rn(aw[i],v)); }
  for (int i=0;i<PL;++i){ acc=__fadd_rn(acc,__fmul_rn(aw[PL+i],pr[i])); }
  logitb[(size_t)gc*KS + k] = acc;
  red[t]=acc; __syncthreads();
  for (int off=128; off; off>>=1){ if(t<off) red[t]+=red[t+off]; __syncthreads(); }
  float tot = red[0];
  __syncthreads();
  red[t]=acc*acc; __syncthreads();
  for (int off=128; off; off>>=1){ if(t<off) red[t]+=red[t+off]; __syncthreads(); }
  if (t==0){ part[blockIdx.x*2]=tot; part[blockIdx.x*2+1]=red[0]; }
}

// ---------------- walk select (BN + d-factor + softmax + hard one-hot) ------
__global__ __launch_bounds__(64) void k_w3(const float* __restrict__ pv, const float* __restrict__ logitb,
                   const float* __restrict__ part, float* __restrict__ curf,
                   const float* __restrict__ pre, float* __restrict__ curves, int* __restrict__ curidx,
                   const float* __restrict__ ag, const float* __restrict__ ab_, int step){
  __shared__ int ks_;
  __shared__ float wv_;
  int gc = blockIdx.x;
  int lane = threadIdx.x;
  float s=0,q=0;
  for (int u=lane; u<100; u+=64){ s+=part[2*u]; q+=part[2*u+1]; }
  s = wsum64(s); q = wsum64(q);
  float me = s/25600.0f;
  float va = fmaxf(q/25600.0f - me*me, 0.f);
  float rs = 1.0f/sqrtf(va+EPSF);
  float g0 = ag[0], b0 = ab_[0];
  const float* pvB = pv + (size_t)gc*KS*PL;
  bool valid = lane < KS;
  float z = 0.f;
  if (valid){
    z = __fadd_rn(__fmul_rn(__fmul_rn(__fsub_rn(logitb[(size_t)gc*KS+lane], me), rs), g0), b0);
    if (step > 0){
      const float* cfo = curf + (size_t)gc*PL;
      const float* pr  = pre + (size_t)gc*PL;
      const float* pvr = pvB + (size_t)lane*PL;
      float dot=0, na=0, nn=0;
      for (int c=0;c<PL;++c){
        float acv = __fsub_rn(cfo[c], pr[c]);
        float nv  = __fsub_rn(pvr[c], cfo[c]);
        dot = __fadd_rn(dot, __fmul_rn(acv,nv));
        na  = __fadd_rn(na, __fmul_rn(acv,acv));
        nn  = __fadd_rn(nn, __fmul_rn(nv,nv));
      }
      float den = fmaxf(__fmul_rn(sqrtf(na), sqrtf(nn)), 1e-8f);
      float d = 1.0f + dot/den;
      d = fminf(fmaxf(d, 0.0f), 1.0f);
      z = __fmul_rn(z, d);
    }
  }
  float mz = valid ? z : -INFINITY;
#pragma unroll
  for (int m=16;m;m>>=1) mz = fmaxf(mz, __shfl_xor(mz, m, 32));
  float e = valid ? expf(z - mz) : 0.f;
  float se = e;
#pragma unroll
  for (int m=16;m;m>>=1) se += __shfl_xor(se, m, 32);
  float y = e / se;
  float bv = valid ? y : -INFINITY; int bi = valid ? lane : 999;
#pragma unroll
  for (int m=16;m;m>>=1){
    float ov=__shfl_xor(bv,m,32); int oi=__shfl_xor(bi,m,32);
    if (ov>bv || (ov==bv && oi<bi)){bv=ov;bi=oi;}
  }
  if (lane==0){
    ks_ = bi;
    wv_ = __fadd_rn(bv, __fsub_rn(1.0f, bv));
    curidx[gc] = bi;
  }
  __syncthreads();
  int kst = ks_; float wval = wv_;
  float val = __fmul_rn(pvB[(size_t)kst*PL + lane], wval);
  curf[(size_t)gc*PL + lane] = val;
  curves[((size_t)gc*CLn + step)*PL + lane] = val;
}

// ---------------- curve aggregation ----------------------------------------
__global__ void k_catt(const float* __restrict__ curves, const float* __restrict__ la, float* __restrict__ catt){
  int u = blockIdx.x*256+threadIdx.x; if (u >= BB*CN*CLn) return;
  const float* cr = curves + (size_t)u*PL;
  float a=0;
  for (int c=0;c<PL;++c) a = __fadd_rn(a, __fmul_rn(la[c], cr[c]));
  catt[u]=a;
}

__global__ __launch_bounds__(256) void k_inter(const float* __restrict__ curves, const float* __restrict__ catt,
                       float* __restrict__ inter0){
  int t=threadIdx.x, wid=t>>6, lane=t&63;
  int gc = blockIdx.x*4+wid;
  const float* at = catt + (size_t)gc*CLn;
  float a0=at[0],a1=at[1],a2=at[2],a3=at[3],a4=at[4];
  float mx = fmaxf(fmaxf(fmaxf(a0,a1),fmaxf(a2,a3)),a4);
  float e0=expf(a0-mx),e1=expf(a1-mx),e2=expf(a2-mx),e3=expf(a3-mx),e4=expf(a4-mx);
  float se = e0+e1+e2+e3+e4;
  const float* cr = curves + (size_t)gc*CLn*PL;
  float acc =           __fmul_rn(cr[lane],        e0/se);
  acc = __fadd_rn(acc, __fmul_rn(cr[PL+lane],     e1/se));
  acc = __fadd_rn(acc, __fmul_rn(cr[2*PL+lane],   e2/se));
  acc = __fadd_rn(acc, __fmul_rn(cr[3*PL+lane],   e3/se));
  acc = __fadd_rn(acc, __fmul_rn(cr[4*PL+lane],   e4/se));
  inter0[(size_t)gc*PL + lane] = acc;
}

__global__ __launch_bounds__(128) void k_intra(const float* __restrict__ curves, const float* __restrict__ catt,
                       float* __restrict__ intra0){
  __shared__ float va[CN], ya[CN];
  int blk = blockIdx.x;
  int b = blk/CLn, l = blk%CLn;
  int t = threadIdx.x;
  if (t < CN) va[t] = catt[(size_t)(b*CN+t)*CLn + l];
  __syncthreads();
  float mx = -INFINITY;
  for (int n=0;n<CN;++n) mx = fmaxf(mx, va[n]);
  if (t < CN) ya[t] = expf(va[t]-mx);
  __syncthreads();
  float se=0;
  for (int n=0;n<CN;++n) se += ya[n];
  if (t < PL){
    float acc=0;
    for (int n=0;n<CN;++n)
      acc = __fadd_rn(acc, __fmul_rn(curves[((size_t)(b*CN+n)*CLn + l)*PL + t], ya[n]/se));
    intra0[(size_t)blk*PL + t] = acc;
  }
}

__global__ __launch_bounds__(256) void k_inter1n(const float* __restrict__ inter0, const float* __restrict__ wa,
                         const float* __restrict__ wn, float* __restrict__ inter1, float* __restrict__ intern){
  __shared__ float i1[4][MD];
  int t=threadIdx.x, wid=t>>6, lane=t&63;
  int gc = blockIdx.x*4+wid;
  const float* r = inter0 + (size_t)gc*PL;
  if (lane < MD){
    float a=0;
    for (int c=0;c<PL;++c) a=__fadd_rn(a,__fmul_rn(wa[lane*PL+c], r[c]));
    inter1[(size_t)gc*MD+lane]=a;
    i1[wid][lane]=a;
  }
  __syncthreads();
  if (lane < MD){
    float a=0;
    for (int i=0;i<MD;++i) a=__fadd_rn(a,__fmul_rn(wn[lane*MD+i], i1[wid][i]));
    intern[(size_t)gc*MD+lane]=a;
  }
}

__global__ __launch_bounds__(64) void k_intra1l(const float* __restrict__ intra0, const float* __restrict__ wb,
                        const float* __restrict__ wl, float* __restrict__ intra1, float* __restrict__ intral){
  __shared__ float i1[MD];
  int blk=blockIdx.x, lane=threadIdx.x;
  const float* r = intra0 + (size_t)blk*PL;
  if (lane<MD){
    float a=0;
    for(int c=0;c<PL;++c) a=__fadd_rn(a,__fmul_rn(wb[lane*PL+c],r[c]));
    intra1[blk*MD+lane]=a; i1[lane]=a;
  }
  __syncthreads();
  if (lane<MD){
    float a=0;
    for(int i=0;i<MD;++i) a=__fadd_rn(a,__fmul_rn(wl[lane*MD+i],i1[i]));
    intral[blk*MD+lane]=a;
  }
}

__global__ __launch_bounds__(256) void k_ca5(const float* __restrict__ h, const float* __restrict__ inter1,
                     const float* __restrict__ intern, const float* __restrict__ intra1,
                     const float* __restrict__ intral, const float* __restrict__ wc,
                     const float* __restrict__ wd, float* __restrict__ yraw, float* __restrict__ part){
  __shared__ float i1[CN*33], in_[CN*33];
  __shared__ float t1[CLn*MD], tl[CLn*MD];
  __shared__ float wdl[PL*65];
  __shared__ float hrow[4][PL];
  __shared__ float xlb[4][MD];
  __shared__ float yb[4][CN];
  __shared__ float cfb[4][PL];
  __shared__ float ssm[4][PL], sq[4][PL];
  int t=threadIdx.x, wid=t>>6, lane=t&63;
  int pg = blockIdx.x;
  int b = pg >> 8;
  int p = (pg & 255)*4 + wid;
  for (int u=t; u<CN*MD; u+=256){ int n=u>>5, m=u&31; i1[n*33+m]=inter1[(size_t)b*CN*MD+u]; in_[n*33+m]=intern[(size_t)b*CN*MD+u]; }
  for (int u=t; u<CLn*MD; u+=256){ t1[u]=intra1[(size_t)b*CLn*MD+u]; tl[u]=intral[(size_t)b*CLn*MD+u]; }
  for (int u=t; u<PL*PL; u+=256){ int c=u>>6,i=u&63; wdl[c*65+i]=wd[u]; }
  hrow[wid][lane] = h[((size_t)b*NP+p)*PL + lane];
  __syncthreads();
  if (lane < MD){
    float a=0;
    for (int c=0;c<PL;++c) a = fmaf(wc[lane*PL+c], hrow[wid][c], a);
    xlb[wid][lane]=a;
  }
  __syncthreads();
  float s0, s1=-INFINITY;
  {
    float a=0;
    for (int m=0;m<MD;++m) a = fmaf(xlb[wid][m], i1[lane*33+m], a);
    s0=a;
    if (lane < CN-64){
      float a2=0; int n2=lane+64;
      for (int m=0;m<MD;++m) a2 = fmaf(xlb[wid][m], i1[n2*33+m], a2);
      s1=a2;
    }
  }
  float mx = fmaxf(s0, s1);
#pragma unroll
  for (int m=32;m;m>>=1) mx = fmaxf(mx, __shfl_xor(mx,m,64));
  float e0 = expf(s0-mx);
  float e1 = (lane < CN-64) ? expf(s1-mx) : 0.f;
  float se = e0+e1;
#pragma unroll
  for (int m=32;m;m>>=1) se += __shfl_xor(se,m,64);
  yb[wid][lane] = e0/se;
  if (lane < CN-64) yb[wid][64+lane] = e1/se;
  __syncthreads();
  if (lane < MD){
    float a=0;
    for (int n=0;n<CN;++n) a = fmaf(yb[wid][n], in_[n*33+lane], a);
    cfb[wid][lane] = a;
  }
  {
    float sl[CLn];
#pragma unroll
    for (int l=0;l<CLn;++l){
      float a=0;
      for (int m=0;m<MD;++m) a = fmaf(xlb[wid][m], t1[l*MD+m], a);
      sl[l]=a;
    }
    float mx2 = fmaxf(fmaxf(fmaxf(sl[0],sl[1]),fmaxf(sl[2],sl[3])),sl[4]);
    float es[CLn]; float ss2=0;
#pragma unroll
    for(int l=0;l<CLn;++l){ es[l]=expf(sl[l]-mx2); ss2+=es[l]; }
    if (lane < MD){
      float a=0;
#pragma unroll
      for (int l=0;l<CLn;++l) a = fmaf(es[l]/ss2, tl[l*MD+lane], a);
      cfb[wid][MD+lane] = a;
    }
  }
  __syncthreads();
  float acc=0;
  for (int i=0;i<PL;++i) acc = fmaf(wdl[lane*65+i], cfb[wid][i], acc);
  yraw[((size_t)b*NP+p)*PL + lane] = acc;
  ssm[wid][lane]=acc; sq[wid][lane]=acc*acc;
  __syncthreads();
  if (t < PL){
    float s2=0,q2=0;
#pragma unroll
    for (int k2=0;k2<4;++k2){ s2+=ssm[k2][t]; q2+=sq[k2][t]; }
    part[((size_t)pg*PL+t)*2]=s2; part[((size_t)pg*PL+t)*2+1]=q2;
  }
}

__global__ __launch_bounds__(256) void k_ca7(const float* __restrict__ h, const float* __restrict__ yraw,
                     const float* __restrict__ mv, const float* __restrict__ dg, const float* __restrict__ db,
                     float* __restrict__ h2){
  int u = blockIdx.x*256+threadIdx.x;
  int c = u & 63;
  float m = mv[2*c]*(1.0f/8192.0f);
  float va = fmaxf(mv[2*c+1]*(1.0f/8192.0f)-m*m, 0.f);
  float rs = 1.0f/sqrtf(va+EPSF);
  float y = yraw[u];
  float v = __fadd_rn(h[u], __fadd_rn(__fmul_rn(__fmul_rn(__fsub_rn(y,m),rs),dg[c]), db[c]));
  h2[u] = lrelu(v);
}

// ---------------- LPFA: staged recompute, wave per point --------------------
template<int STAGE>
__global__ __launch_bounds__(256) void k_lp(const float* __restrict__ nxyz, const int* __restrict__ knnI,
                    const float* __restrict__ h2,
                    const float* __restrict__ xw, const float* __restrict__ w1, const float* __restrict__ w2,
                    const float* __restrict__ mv1, const float* __restrict__ mv2, const float* __restrict__ mv3,
                    const float* __restrict__ g1, const float* __restrict__ b1,
                    const float* __restrict__ g2, const float* __restrict__ b2,
                    const float* __restrict__ g3, const float* __restrict__ b3,
                    float* __restrict__ part, float* __restrict__ lpout){
  __shared__ float pfb[4][KS*10];
  __shared__ int   nbl[4][KS];
  __shared__ __align__(16) float fbuf[4][PL*36];
  __shared__ float ssm[4][PL], sq[4][PL];
  int t=threadIdx.x, wid=t>>6, lane=t&63;
  int pt = blockIdx.x*4+wid;
  int b = pt >> 10;
  if (lane < KS){
    int nb = knnI[(size_t)pt*33 + lane];
    nbl[wid][lane] = nb;
    float cx=nxyz[(size_t)pt*3], cy=nxyz[(size_t)pt*3+1], cz=nxyz[(size_t)pt*3+2];
    size_t nbg = (size_t)b*NP + nb;
    float nx=nxyz[nbg*3], ny=nxyz[nbg*3+1], nz=nxyz[nbg*3+2];
    float* pf = &pfb[wid][lane*10];
    pf[0]=cx; pf[1]=cy; pf[2]=cz; pf[3]=nx; pf[4]=ny; pf[5]=nz;
    pf[6]=__fsub_rn(nx,cx); pf[7]=__fsub_rn(ny,cy); pf[8]=__fsub_rn(nz,cz);
  }
  __syncthreads();
  float xwr[9];
#pragma unroll
  for (int i=0;i<9;++i) xwr[i] = xw[lane*9+i];
  float c1v[KS];
#pragma unroll
  for (int j=0;j<KS;++j){
    float a=0;
#pragma unroll
    for (int i=0;i<9;++i) a = fmaf(xwr[i], pfb[wid][j*10+i], a);
    c1v[j]=a;
  }
  if (STAGE == 1){
    float s=0,qq=0;
#pragma unroll
    for (int j=0;j<KS;++j){ s+=c1v[j]; qq+=c1v[j]*c1v[j]; }
    ssm[wid][lane]=s; sq[wid][lane]=qq;
    __syncthreads();
    if (t<PL){
      float s2=0,q2=0;
#pragma unroll
      for(int k2=0;k2<4;++k2){s2+=ssm[k2][t];q2+=sq[k2][t];}
      part[((size_t)blockIdx.x*PL+t)*2]=s2; part[((size_t)blockIdx.x*PL+t)*2+1]=q2;
    }
    return;
  }
  constexpr float CT = 1.0f/262144.0f;
  float m1 = mv1[2*lane]*CT; float va1=fmaxf(mv1[2*lane+1]*CT-m1*m1,0.f); float rs1=1.0f/sqrtf(va1+EPSF);
  float hc = h2[(size_t)pt*PL + lane];
  float g1v=g1[lane], b1v=b1[lane];
#pragma unroll
  for (int j=0;j<KS;++j){
    float fd = __fsub_rn(h2[((size_t)b*NP + nbl[wid][j])*PL + lane], hc);
    float bn1 = __fadd_rn(__fmul_rn(__fmul_rn(__fsub_rn(c1v[j],m1),rs1),g1v),b1v);
    fbuf[wid][lane*36+j] = lrelu(__fadd_rn(fd, bn1));
  }
  __syncthreads();
  float wr[PL];
#pragma unroll
  for (int i=0;i<PL;++i) wr[i] = w1[lane*PL+i];
  float acc[KS];
#pragma unroll
  for (int j=0;j<KS;++j) acc[j]=0;
#pragma unroll
  for (int cp=0;cp<PL;++cp){
    const float4* rp = reinterpret_cast<const float4*>(&fbuf[wid][cp*36]);
    float wv = wr[cp];
#pragma unroll
    for (int j4=0;j4<8;++j4){
      float4 f = rp[j4];
      acc[j4*4+0] = fmaf(wv, f.x, acc[j4*4+0]);
      acc[j4*4+1] = fmaf(wv, f.y, acc[j4*4+1]);
      acc[j4*4+2] = fmaf(wv, f.z, acc[j4*4+2]);
      acc[j4*4+3] = fmaf(wv, f.w, acc[j4*4+3]);
    }
  }
  if (STAGE == 2){
    float s=0,qq=0;
#pragma unroll
    for (int j=0;j<KS;++j){ s+=acc[j]; qq+=acc[j]*acc[j]; }
    ssm[wid][lane]=s; sq[wid][lane]=qq;
    __syncthreads();
    if (t<PL){
      float s2=0,q2=0;
#pragma unroll
      for(int k2=0;k2<4;++k2){s2+=ssm[k2][t];q2+=sq[k2][t];}
      part[((size_t)blockIdx.x*PL+t)*2]=s2; part[((size_t)blockIdx.x*PL+t)*2+1]=q2;
    }
    return;
  }
  float m2 = mv2[2*lane]*CT; float va2=fmaxf(mv2[2*lane+1]*CT-m2*m2,0.f); float rs2=1.0f/sqrtf(va2+EPSF);
  float g2v=g2[lane], b2v=b2[lane];
  __syncthreads();
#pragma unroll
  for (int j=0;j<KS;++j){
    float f2 = lrelu(__fadd_rn(__fmul_rn(__fmul_rn(__fsub_rn(acc[j],m2),rs2),g2v),b2v));
    fbuf[wid][lane*36+j] = f2;
  }
  __syncthreads();
#pragma unroll
  for (int i=0;i<PL;++i) wr[i] = w2[lane*PL+i];
#pragma unroll
  for (int j=0;j<KS;++j) acc[j]=0;
#pragma unroll
  for (int cp=0;cp<PL;++cp){
    const float4* rp = reinterpret_cast<const float4*>(&fbuf[wid][cp*36]);
    float wv = wr[cp];
#pragma unroll
    for (int j4=0;j4<8;++j4){
      float4 f = rp[j4];
      acc[j4*4+0] = fmaf(wv, f.x, acc[j4*4+0]);
      acc[j4*4+1] = fmaf(wv, f.y, acc[j4*4+1]);
      acc[j4*4+2] = fmaf(wv, f.z, acc[j4*4+2]);
      acc[j4*4+3] = fmaf(wv, f.w, acc[j4*4+3]);
    }
  }
  if (STAGE == 3){
    float s=0,qq=0;
#pragma unroll
    for (int j=0;j<KS;++j){ s+=acc[j]; qq+=acc[j]*acc[j]; }
    ssm[wid][lane]=s; sq[wid][lane]=qq;
    __syncthreads();
    if (t<PL){
      float s2=0,q2=0;
#pragma unroll
      for(int k2=0;k2<4;++k2){s2+=ssm[k2][t];q2+=sq[k2][t];}
      part[((size_t)blockIdx.x*PL+t)*2]=s2; part[((size_t)blockIdx.x*PL+t)*2+1]=q2;
    }
    return;
  }
  float m3 = mv3[2*lane]*CT; float va3=fmaxf(mv3[2*lane+1]*CT-m3*m3,0.f); float rs3=1.0f/sqrtf(va3+EPSF);
  float g3v=g3[lane], b3v=b3[lane];
  float sum=0;
#pragma unroll
  for (int j=0;j<KS;++j){
    float f3 = lrelu(__fadd_rn(__fmul_rn(__fmul_rn(__fsub_rn(acc[j],m3),rs3),g3v),b3v));
    sum = __fadd_rn(sum, f3);
  }
  lpout[(size_t)pt*PL + lane] = __fmul_rn(sum, (1.0f/32.0f));
}

// ---------------- output convs ----------------------------------------------
__global__ __launch_bounds__(256) void k_fc1(const float* __restrict__ lpout, const float* __restrict__ w,
                     float* __restrict__ y2raw, float* __restrict__ part){
  __shared__ float wl[128*65];
  __shared__ float xr[4][PL];
  __shared__ float ssm[4][128], sq[4][128];
  int t=threadIdx.x, wid=t>>6, lane=t&63;
  int pg = blockIdx.x >> 1;
  int half = blockIdx.x & 1;
  int pt = pg*4 + wid;
  for (int u=t; u<128*PL; u+=256){ int c=u>>6, i=u&63; wl[c*65+i] = w[(size_t)half*128*PL + u]; }
  xr[wid][lane] = lpout[(size_t)pt*PL + lane];
  __syncthreads();
  float a0=0, a1=0;
  for (int i=0;i<PL;++i){
    float xv = xr[wid][i];
    a0 = fmaf(wl[lane*65+i], xv, a0);
    a1 = fmaf(wl[(lane+64)*65+i], xv, a1);
  }
  y2raw[(size_t)pt*CO + half*128 + lane]      = a0;
  y2raw[(size_t)pt*CO + half*128 + 64 + lane] = a1;
  ssm[wid][lane]=a0; ssm[wid][64+lane]=a1; sq[wid][lane]=a0*a0; sq[wid][64+lane]=a1*a1;
  __syncthreads();
  if (t < 128){
    float s=0,qq=0;
#pragma unroll
    for(int k2=0;k2<4;++k2){ s+=ssm[k2][t]; qq+=sq[k2][t]; }
    part[((size_t)pg*CO + half*128 + t)*2]   = s;
    part[((size_t)pg*CO + half*128 + t)*2+1] = qq;
  }
}

__global__ __launch_bounds__(256) void k_fc2(const float* __restrict__ xnew, const float* __restrict__ w,
                     float* __restrict__ scraw, float* __restrict__ part){
  __shared__ float wl[64*129];
  __shared__ float xr[4][CI];
  __shared__ float ssm[4][64], sq[4][64];
  int t=threadIdx.x, wid=t>>6, lane=t&63;
  int pg = blockIdx.x >> 2;
  int qr = blockIdx.x & 3;
  int pt = pg*4 + wid;
  for (int u=t; u<64*CI; u+=256){ int c=u>>7, i=u&127; wl[c*129+i] = w[(size_t)qr*64*CI + u]; }
  xr[wid][lane]    = xnew[(size_t)pt*CI+lane];
  xr[wid][lane+64] = xnew[(size_t)pt*CI+lane+64];
  __syncthreads();
  float a=0;
  for (int i=0;i<CI;++i) a = fmaf(wl[lane*129+i], xr[wid][i], a);
  scraw[(size_t)pt*CO + qr*64 + lane] = a;
  ssm[wid][lane]=a; sq[wid][lane]=a*a;
  __syncthreads();
  if (t<64){
    float s=0,qq=0;
#pragma unroll
    for(int k2=0;k2<4;++k2){ s+=ssm[k2][t]; qq+=sq[k2][t]; }
    part[((size_t)pg*CO + qr*64 + t)*2]   = s;
    part[((size_t)pg*CO + qr*64 + t)*2+1] = qq;
  }
}

__global__ __launch_bounds__(256) void k_fc3(const float* __restrict__ y2raw, const float* __restrict__ scraw,
                     const float* __restrict__ mvfc, const float* __restrict__ mvsc,
                     const float* __restrict__ g2, const float* __restrict__ b2,
                     const float* __restrict__ gs, const float* __restrict__ bs,
                     float* __restrict__ outp){
  int u = blockIdx.x*256+threadIdx.x;
  int p = u & 1023;
  int c = (u >> 10) & 255;
  int b = u >> 18;
  float mo = mvfc[2*c]*(1.0f/8192.0f); float vo=fmaxf(mvfc[2*c+1]*(1.0f/8192.0f)-mo*mo,0.f); float ro=1.0f/sqrtf(vo+EPSF);
  float ms = mvsc[2*c]*(1.0f/8192.0f); float vs=fmaxf(mvsc[2*c+1]*(1.0f/8192.0f)-ms*ms,0.f); float rs=1.0f/sqrtf(vs+EPSF);
  float y = y2raw[((size_t)b*NP+p)*CO + c];
  float s = scraw[((size_t)b*NP+p)*CO + c];
  float v1 = __fadd_rn(__fmul_rn(__fmul_rn(__fsub_rn(y,mo),ro),g2[c]), b2[c]);
  float v2 = __fadd_rn(__fmul_rn(__fmul_rn(__fsub_rn(s,ms),rs),gs[c]), bs[c]);
  outp[u] = lrelu(__fadd_rn(v1,v2));
}

__global__ void k_xyzd(const float* __restrict__ nxyz, float* __restrict__ outp){
  int u = blockIdx.x*256+threadIdx.x; if (u >= BB*3*NP) return;
  int s = u & 1023;
  int c = (u>>10)%3;
  int b = u/(3*NP);
  outp[u] = nxyz[((size_t)b*NP+s)*3 + c];
}

} // anonymous namespace

extern "C" void kernel_launch(void* const* d_in, const int* in_sizes, int n_in,
                              void* d_out, int out_size, void* d_ws, size_t ws_size,
                              hipStream_t stream){
  const float* xyz  = (const float*)d_in[0];
  const float* xin  = (const float*)d_in[1];
  const float* c1w  = (const float*)d_in[2];
  const float* c1g  = (const float*)d_in[3];
  const float* c1b  = (const float*)d_in[4];
  const float* c2w  = (const float*)d_in[5];
  const float* c2g  = (const float*)d_in[6];
  const float* c2b  = (const float*)d_in[7];
  const float* scw  = (const float*)d_in[8];
  const float* scg  = (const float*)d_in[9];
  const float* scb  = (const float*)d_in[10];
  const float* attw = (const float*)d_in[11];
  const float* aw   = (const float*)d_in[12];
  const float* ag   = (const float*)d_in[13];
  const float* abv  = (const float*)d_in[14];
  const float* mw   = (const float*)d_in[15];
  const float* mg   = (const float*)d_in[16];
  const float* mb_  = (const float*)d_in[17];
  const float* law  = (const float*)d_in[18];
  const float* waw  = (const float*)d_in[19];
  const float* wbw  = (const float*)d_in[20];
  const float* wcw  = (const float*)d_in[21];
  const float* wnw  = (const float*)d_in[22];
  const float* wlw  = (const float*)d_in[23];
  const float* wdw  = (const float*)d_in[24];
  const float* dg   = (const float*)d_in[25];
  const float* db   = (const float*)d_in[26];
  const float* xfw  = (const float*)d_in[27];
  const float* xfg  = (const float*)d_in[28];
  const float* xfb  = (const float*)d_in[29];
  const float* m1w  = (const float*)d_in[30];
  const float* m1g  = (const float*)d_in[31];
  const float* m1b  = (const float*)d_in[32];
  const float* m2w  = (const float*)d_in[33];
  const float* m2g  = (const float*)d_in[34];
  const float* m2b  = (const float*)d_in[35];
  float* outp = (float*)d_out;

  char* base = (char*)d_ws;
  size_t off = 0;
  auto alloc = [&](size_t nbytes)->void*{ void* p = base + off; off = (off + nbytes + 255) & ~(size_t)255; return p; };
  int*   fpsI   = (int*)  alloc(sizeof(int)*BB*NP);
  float* sx     = (float*)alloc(sizeof(float)*BB*NN);
  float* nxyz   = (float*)alloc(sizeof(float)*BB*NP*3);
  float* nxx    = (float*)alloc(sizeof(float)*BB*NP);
  int*   gidx   = (int*)  alloc(sizeof(int)*BB*NP*KS);
  float* xt     = (float*)alloc(sizeof(float)*(size_t)BB*NN*CI);
  float* xnew   = (float*)alloc(sizeof(float)*(size_t)BB*NP*CI);
  float* hraw   = (float*)alloc(sizeof(float)*(size_t)BB*NP*PL);
  float* hbuf   = (float*)alloc(sizeof(float)*(size_t)BB*NP*PL);
  float* attv   = (float*)alloc(sizeof(float)*BB*NP);
  float* wxt    = (float*)alloc(sizeof(float)*(size_t)BB*NP*PL);
  int*   knnI   = (int*)  alloc(sizeof(int)*BB*NP*33);
  int*   startb = (int*)  alloc(sizeof(int)*BB*CN);
  float* pre    = (float*)alloc(sizeof(float)*BB*CN*PL);
  float* curf   = (float*)alloc(sizeof(float)*BB*CN*PL);
  int*   curidx = (int*)  alloc(sizeof(int)*BB*CN);
  float* pv     = (float*)alloc(sizeof(float)*(size_t)BB*CN*KS*PL);
  float* logitb = (float*)alloc(sizeof(float)*BB*CN*KS);
  float* curves = (float*)alloc(sizeof(float)*BB*CN*CLn*PL);
  float* catt   = (float*)alloc(sizeof(float)*BB*CN*CLn);
  float* inter0 = (float*)alloc(sizeof(float)*BB*CN*PL);
  float* intra0 = (float*)alloc(sizeof(float)*BB*CLn*PL);
  float* inter1 = (float*)alloc(sizeof(float)*BB*CN*MD);
  float* intern = (float*)alloc(sizeof(float)*BB*CN*MD);
  float* intra1 = (float*)alloc(sizeof(float)*BB*CLn*MD);
  float* intral = (float*)alloc(sizeof(float)*BB*CLn*MD);
  float* yraw   = (float*)alloc(sizeof(float)*(size_t)BB*NP*PL);
  float* h2     = (float*)alloc(sizeof(float)*(size_t)BB*NP*PL);
  float* lpout  = (float*)alloc(sizeof(float)*(size_t)BB*NP*PL);
  float* y2raw  = (float*)alloc(sizeof(float)*(size_t)BB*NP*CO);
  float* scraw  = (float*)alloc(sizeof(float)*(size_t)BB*NP*CO);
  float* part   = (float*)alloc(sizeof(float)*(size_t)2048*CO*2);
  float* mvA    = (float*)alloc(sizeof(float)*2048);
  float* mvC1 = mvA;
  float* mvWD = mvA + 128;
  float* mvL1 = mvA + 256;
  float* mvL2 = mvA + 384;
  float* mvL3 = mvA + 512;
  float* mvFC = mvA + 640;
  float* mvSC = mvA + 1152;

  k_fps<<<BB, 256, 0, stream>>>(xyz, fpsI);
  k_sx<<<(BB*NN)/256, 256, 0, stream>>>(xyz, sx);
  k_newxyz<<<(BB*NP)/256, 256, 0, stream>>>(xyz, fpsI, nxyz, nxx);
  k_ball<<<(BB*NP)/4, 256, 0, stream>>>(xyz, sx, nxyz, nxx, gidx);
  k_transpose<<<BB*256, 256, 0, stream>>>(xin, xt);
  k_groupmax<<<BB*NP, 128, 0, stream>>>(xt, gidx, xnew);
  k_conv1<<<(BB*NP)/4, 256, 0, stream>>>(xnew, c1w, hraw, part);
  k_red<<<128, 256, 0, stream>>>(part, mvC1, 2048, 128);
  k_n1<<<(BB*NP)/4, 256, 0, stream>>>(hraw, mvC1, c1g, c1b, attw, hbuf, attv, wxt);
  k_knn<<<(BB*NP)/4, 256, 0, stream>>>(nxyz, nxx, knnI);
  k_start<<<BB, 64, 0, stream>>>(attv, startb);
  k_w0<<<(BB*CN)/4, 256, 0, stream>>>(wxt, startb, pre, curidx);
  for (int step = 0; step < CLn; ++step){
    if (step > 0) k_wmom<<<1, 256, 0, stream>>>(curf, pre, mw, mg, mb_);
    k_w2<<<(BB*CN)/8, 256, 0, stream>>>(wxt, pre, knnI, curidx, aw, pv, logitb, part);
    k_w3<<<BB*CN, 64, 0, stream>>>(pv, logitb, part, curf, pre, curves, curidx, ag, abv, step);
  }
  k_catt<<<(BB*CN*CLn + 255)/256, 256, 0, stream>>>(curves, law, catt);
  k_inter<<<(BB*CN)/4, 256, 0, stream>>>(curves, catt, inter0);
  k_intra<<<BB*CLn, 128, 0, stream>>>(curves, catt, intra0);
  k_inter1n<<<(BB*CN)/4, 256, 0, stream>>>(inter0, waw, wnw, inter1, intern);
  k_intra1l<<<BB*CLn, 64, 0, stream>>>(intra0, wbw, wlw, intra1, intral);
  k_ca5<<<(BB*NP)/4, 256, 0, stream>>>(hbuf, inter1, intern, intra1, intral, wcw, wdw, yraw, part);
  k_red<<<128, 256, 0, stream>>>(part, mvWD, 2048, 128);
  k_ca7<<<(BB*NP*PL)/256, 256, 0, stream>>>(hbuf, yraw, mvWD, dg, db, h2);
  k_lp<1><<<(BB*NP)/4, 256, 0, stream>>>(nxyz, knnI, h2, xfw, m1w, m2w, mvL1, mvL2, mvL3, xfg, xfb, m1g, m1b, m2g, m2b, part, lpout);
  k_red<<<128, 256, 0, stream>>>(part, mvL1, 2048, 128);
  k_lp<2><<<(BB*NP)/4, 256, 0, stream>>>(nxyz, knnI, h2, xfw, m1w, m2w, mvL1, mvL2, mvL3, xfg, xfb, m1g, m1b, m2g, m2b, part, lpout);
  k_red<<<128, 256, 0, stream>>>(part, mvL2, 2048, 128);
  k_lp<3><<<(BB*NP)/4, 256, 0, stream>>>(nxyz, knnI, h2, xfw, m1w, m2w, mvL1, mvL2, mvL3, xfg, xfb, m1g, m1b, m2g, m2b, part, lpout);
  k_red<<<128, 256, 0, stream>>>(part, mvL3, 2048, 128);
  k_lp<4><<<(BB*NP)/4, 256, 0, stream>>>(nxyz, knnI, h2, xfw, m1w, m2w, mvL1, mvL2, mvL3, xfg, xfb, m1g, m1b, m2g, m2b, part, lpout);
  k_fc1<<<((BB*NP)/4)*2, 256, 0, stream>>>(lpout, c2w, y2raw, part);
  k_red<<<512, 256, 0, stream>>>(part, mvFC, 2048, 512);
  k_fc2<<<((BB*NP)/4)*4, 256, 0, stream>>>(xnew, scw, scraw, part);
  k_red<<<512, 256, 0, stream>>>(part, mvSC, 2048, 512);
  k_fc3<<<(BB*CO*NP)/256, 256, 0, stream>>>(y2raw, scraw, mvFC, mvSC, c2g, c2b, scg, scb, outp + BB*3*NP);
  k_xyzd<<<(BB*3*NP + 255)/256, 256, 0, stream>>>(nxyz, outp);
}